// Round 16
// baseline (445.525 us; speedup 1.0000x reference)
//
#include <hip/hip_runtime.h>
#include <hip/hip_bf16.h>
#include <cmath>
#include <cstdint>

typedef __bf16 bf16;
typedef __bf16 bf16x8 __attribute__((ext_vector_type(8)));
typedef __bf16 bf16x4 __attribute__((ext_vector_type(4)));
typedef float  f32x4  __attribute__((ext_vector_type(4)));

constexpr int B_   = 4;
constexpr int S_   = 2048;
constexpr int D_   = 1024;
constexpr int H_   = 16;
constexpr int DFF_ = 4096;
constexpr int TD_  = 256;
constexpr int KEEP = 1433;              // int(2048*0.7)
constexpr int M_TOT = B_ * KEEP;        // 5732
constexpr int MPAD  = 5888;             // 46*128
constexpr int QT64  = (KEEP + 63) / 64; // 23
constexpr int NKV   = (KEEP + 63) / 64; // 23
constexpr float EPS = 1e-5f;
// 1/sqrt(64) * log2(e): folded into Q in the QKV epilogue; attn uses exp2.
constexpr float QSCALE = 0.18033688011112042f;

__device__ __forceinline__ f32x4 mfma16(bf16x8 a, bf16x8 b, f32x4 c) {
  return __builtin_amdgcn_mfma_f32_16x16x32_bf16(a, b, c, 0, 0, 0);
}

#define GLOAD_LDS(gp, lp)                                                     \
  __builtin_amdgcn_global_load_lds(                                           \
      (const __attribute__((address_space(1))) void*)(gp),                    \
      (__attribute__((address_space(3))) void*)(lp), 16, 0, 0)

// ---------------- fused prep ------------------------------------------------
// [0,2048)     importance GEMV; ublk = bid>>9 (slow index -> all 4 u-chunks of
//              the same tokens land on the SAME XCD; x re-reads become L2 hits)
// [2048,3584)  fp32->bf16 weight casts, 8 float4/thread
// [3584,4608)  d_out = x copy, 8 float4/thread
// [4608,8704)  cond projections x2
__global__ __launch_bounds__(256) void k_prep(
    const float* __restrict__ x, const float* __restrict__ tr_w1,
    double* __restrict__ hidden,
    const float* __restrict__ in_w, const float* __restrict__ out_w,
    const float* __restrict__ f1_w, const float* __restrict__ f2_w,
    bf16* __restrict__ w_in, bf16* __restrict__ w_out,
    bf16* __restrict__ w_f1, bf16* __restrict__ w_f2,
    float* __restrict__ dout,
    const float* __restrict__ temb,
    const float* __restrict__ ln1_w, const float* __restrict__ ln1_b,
    float* __restrict__ p1,
    const float* __restrict__ ln2_w, const float* __restrict__ ln2_b,
    float* __restrict__ p2)
{
  const int bid = blockIdx.x;
  if (bid < 2048) {
    // ---- importance GEMV: 4 tokens x 8 units per wave, fp64 accumulate
    const int lane = threadIdx.x & 63, w = threadIdx.x >> 6;
    const int tok0 = (bid & 511) * 16 + w * 4;
    const int u0 = (bid >> 9) * 8;
    const float* xb = x + (size_t)tok0 * D_ + lane * 4;
    const float* wb = tr_w1 + (size_t)u0 * D_ + lane * 4;
    double acc[4][8] = {};
#pragma unroll 2
    for (int c = 0; c < D_; c += 256) {
      float4 xv[4], wv[8];
#pragma unroll
      for (int i = 0; i < 4; ++i)
        xv[i] = *(const float4*)(xb + (size_t)i * D_ + c);
#pragma unroll
      for (int u = 0; u < 8; ++u)
        wv[u] = *(const float4*)(wb + (size_t)u * D_ + c);
#pragma unroll
      for (int i = 0; i < 4; ++i)
#pragma unroll
        for (int u = 0; u < 8; ++u) {
          acc[i][u] += (double)xv[i].x * (double)wv[u].x;
          acc[i][u] += (double)xv[i].y * (double)wv[u].y;
          acc[i][u] += (double)xv[i].z * (double)wv[u].z;
          acc[i][u] += (double)xv[i].w * (double)wv[u].w;
        }
    }
#pragma unroll
    for (int i = 0; i < 4; ++i)
#pragma unroll
      for (int u = 0; u < 8; ++u) {
        double s = acc[i][u];
        for (int o = 32; o > 0; o >>= 1) s += __shfl_xor(s, o);
        acc[i][u] = s;
      }
    if (lane == 0) {
#pragma unroll
      for (int i = 0; i < 4; ++i)
#pragma unroll
        for (int u = 0; u < 8; ++u)
          hidden[(size_t)(tok0 + i) * 32 + u0 + u] = acc[i][u];
    }
  } else if (bid < 3584) {
    // ---- fp32 -> bf16 weight casts: 8 float4 per thread
    const int base = (bid - 2048) * 2048 + threadIdx.x;
#pragma unroll
    for (int k2 = 0; k2 < 8; ++k2) {
      const int g = base + k2 * 256;
      const float* src; bf16* dst; int off;
      if (g < 786432)       { src = in_w;  dst = w_in;  off = g; }
      else if (g < 1048576) { src = out_w; dst = w_out; off = g - 786432; }
      else if (g < 2097152) { src = f1_w;  dst = w_f1;  off = g - 1048576; }
      else                  { src = f2_w;  dst = w_f2;  off = g - 2097152; }
      float4 v = ((const float4*)src)[off];
      bf16x4 o = {(bf16)v.x, (bf16)v.y, (bf16)v.z, (bf16)v.w};
      ((bf16x4*)dst)[off] = o;
    }
  } else if (bid < 4608) {
    // ---- d_out = x: 8 float4 per thread
    const int base = (bid - 3584) * 2048 + threadIdx.x;
    float4 v[8];
#pragma unroll
    for (int k2 = 0; k2 < 8; ++k2) v[k2] = ((const float4*)x)[base + k2 * 256];
#pragma unroll
    for (int k2 = 0; k2 < 8; ++k2) ((float4*)dout)[base + k2 * 256] = v[k2];
  } else {
    // ---- cond projections
    int gw = (int)(((bid - 4608) * 256 + threadIdx.x) >> 6);
    const int lane = threadIdx.x & 63;
    const float* W = ln1_w; const float* bias = ln1_b; float* p = p1;
    if (gw >= 8192) { gw -= 8192; W = ln2_w; bias = ln2_b; p = p2; }
    const int b = gw >> 11;
    const int row = gw & 2047;
    const float* te = temb + (size_t)b * TD_;
    const float* wr = W + (size_t)row * TD_;
    float acc = 0.f;
    for (int i = lane; i < TD_; i += 64) {
      float c = te[i];
      acc += (c / (1.f + __expf(-c))) * wr[i];
    }
    for (int o = 32; o > 0; o >>= 1) acc += __shfl_down(acc, o);
    if (lane == 0) p[(size_t)b * 2 * D_ + row] = acc + bias[row];
  }
}

// ---------------- importance tail: imp = silu(hidden + b1) . w2 + b2 --------
__global__ __launch_bounds__(256) void k_imptail(
    const double* __restrict__ hidden, const float* __restrict__ b1,
    const float* __restrict__ w2, const float* __restrict__ b2,
    double* __restrict__ imp)
{
  const int tok = blockIdx.x * 256 + threadIdx.x;
  const double* hp = hidden + (size_t)tok * 32;
  double r = 0.0;
#pragma unroll
  for (int u = 0; u < 32; ++u) {
    double s = hp[u] + (double)b1[u];
    double sv = s / (1.0 + exp(-s));
    r += sv * (double)w2[u];
  }
  imp[tok] = r + (double)b2[0];
}

// ---------------- rank: #(greater) or (equal && earlier) ---------------------
__global__ __launch_bounds__(256) void k_rank(const double* __restrict__ imp,
                                              int* __restrict__ rank)
{
  const int b = blockIdx.x >> 5;
  const int seg = blockIdx.x & 31;     // 64 tokens per block
  __shared__ double vals[S_];
  const double* ib = imp + (size_t)b * S_;
  for (int i = threadIdx.x; i < S_ / 2; i += 256)
    ((double2*)vals)[i] = ((const double2*)ib)[i];
  __syncthreads();
  const int tl = threadIdx.x >> 2;     // token within segment
  const int part = threadIdx.x & 3;    // quarter of the scan
  const int s = seg * 64 + tl;
  const double v = vals[s];
  int cnt = 0;
  for (int j = part * 512; j < (part + 1) * 512; ++j) {
    double u = vals[j];
    cnt += (u > v) || (u == v && j < s);
  }
  cnt += __shfl_xor(cnt, 1);
  cnt += __shfl_xor(cnt, 2);
  if (part == 0) rank[b * S_ + s] = cnt;
}

// ---------------- compact kept indices (ascending) ---------------------------
__global__ __launch_bounds__(256) void k_compact(const int* __restrict__ rank,
                                                 int* __restrict__ idx)
{
  const int b = blockIdx.x;
  __shared__ int wcnt[4];
  __shared__ int base_s;
  if (threadIdx.x == 0) base_s = 0;
  __syncthreads();
  const int t = threadIdx.x, lane = t & 63, w = t >> 6;
  for (int c = 0; c < S_ / 256; ++c) {
    const int s = c * 256 + t;
    const bool kept = rank[b * S_ + s] < KEEP;
    unsigned long long m = __ballot(kept);
    int piw = __popcll(m & ((1ull << lane) - 1ull));
    if (lane == 0) wcnt[w] = __popcll(m);
    __syncthreads();
    int off = base_s;
    for (int i = 0; i < w; ++i) off += wcnt[i];
    if (kept) idx[b * KEEP + off + piw] = s;
    __syncthreads();
    if (t == 0) base_s += wcnt[0] + wcnt[1] + wcnt[2] + wcnt[3];
    __syncthreads();
  }
}

// ---------------- gather + adaLN -> bf16 -------------------------------------
__global__ __launch_bounds__(256) void k_adaln(
    const float* __restrict__ xsrc, const int* __restrict__ idx,
    const float* __restrict__ p, bf16* __restrict__ hout)
{
  const int r = blockIdx.x, t = threadIdx.x;
  bf16* orow = hout + (size_t)r * D_;
  if (r >= M_TOT) {
    bf16x4 z = {(bf16)0.f, (bf16)0.f, (bf16)0.f, (bf16)0.f};
    ((bf16x4*)orow)[t] = z;
    return;
  }
  const int b = r / KEEP, j = r - b * KEEP;
  const int s = idx[b * KEEP + j];
  const float* xr = xsrc + ((size_t)(b * S_ + s)) * D_;
  float4 v = ((const float4*)xr)[t];
  __shared__ float red[8];
  float sum = v.x + v.y + v.z + v.w;
  for (int o = 32; o > 0; o >>= 1) sum += __shfl_down(sum, o);
  const int lane = t & 63, w = t >> 6;
  if (lane == 0) red[w] = sum;
  __syncthreads();
  const float mu = (red[0] + red[1] + red[2] + red[3]) * (1.f / D_);
  const float dx = v.x - mu, dy = v.y - mu, dz = v.z - mu, dw = v.w - mu;
  float vs = dx * dx + dy * dy + dz * dz + dw * dw;
  for (int o = 32; o > 0; o >>= 1) vs += __shfl_down(vs, o);
  if (lane == 0) red[4 + w] = vs;
  __syncthreads();
  const float rstd = rsqrtf((red[4] + red[5] + red[6] + red[7]) * (1.f / D_) + EPS);
  const float* gp = p + (size_t)b * 2 * D_;
  float4 g  = ((const float4*)gp)[t];
  float4 be = ((const float4*)(gp + D_))[t];
  bf16x4 o;
  o[0] = (bf16)(dx * rstd * (1.f + g.x) + be.x);
  o[1] = (bf16)(dy * rstd * (1.f + g.y) + be.y);
  o[2] = (bf16)(dz * rstd * (1.f + g.z) + be.z);
  o[3] = (bf16)(dw * rstd * (1.f + g.w) + be.w);
  ((bf16x4*)orow)[t] = o;
}

// ---------------- GEMM 128xBN, BK=32 (32KB LDS, 3 blk/CU) -------------------
// 2-phase dbuf, 2-bit chunk swizzle, hoisted staging, bijective XCD remap.
// MODE 0: bias (+QSCALE on Q third) -> bf16. MODE 1: bias+gelu -> bf16.
// MODE 2: bias, then resid[row(m)][n] += gate[n]*v (gathered residual).
template <int BN, int MODE>
__global__ __launch_bounds__(256) void k_gemm(
    const bf16* __restrict__ A, const bf16* __restrict__ W,
    const float* __restrict__ bias, bf16* __restrict__ Cbf,
    const float* __restrict__ gate, const int* __restrict__ idx,
    float* __restrict__ resid, int N, int K, int gn)
{
  constexpr int WN = BN / 2;      // per-wave N span
  constexpr int NJ = WN / 16;     // N fragments per wave
  constexpr int WIT = BN / 64;    // W staging rounds (BN*32 / 2048)
  __shared__ bf16 As[2][128 * 32];
  __shared__ bf16 Ws[2][BN * 32];
  const int t = threadIdx.x, lane = t & 63;
  const int w = t >> 6, wr = w >> 1, wc = w & 1;
  const int fr = lane & 15, fq = lane >> 4;

  // bijective XCD-contiguous remap (m204)
  const int nwg = gridDim.x, orig = blockIdx.x;
  const int q8 = nwg >> 3, r8 = nwg & 7;
  const int xc = orig & 7, pos = orig >> 3;
  const int wgid = (xc < r8 ? xc * (q8 + 1) : r8 * (q8 + 1) + (xc - r8) * q8) + pos;
  const int bm = wgid / gn, bn = wgid - bm * gn;

  const bf16* Ab = A + (size_t)bm * 128 * K;
  const bf16* Wb = W + (size_t)bn * BN * K;

  const bf16* pA[2];
  const bf16* pW[WIT];
#pragma unroll
  for (int it = 0; it < 2; ++it) {
    const int e = it * 256 + t;
    const int row = e >> 2, pc = e & 3;
    const int lc = pc ^ (row & 3);
    pA[it] = Ab + (size_t)row * K + lc * 8;
  }
#pragma unroll
  for (int it = 0; it < WIT; ++it) {
    const int e = it * 256 + t;
    const int row = e >> 2, pc = e & 3;
    const int lc = pc ^ (row & 3);
    pW[it] = Wb + (size_t)row * K + lc * 8;
  }

  auto stage = [&](int buf) {
#pragma unroll
    for (int it = 0; it < 2; ++it) {
      GLOAD_LDS(pA[it], &As[buf][0] + (it * 256 + t) * 8);
      pA[it] += 32;
    }
#pragma unroll
    for (int it = 0; it < WIT; ++it) {
      GLOAD_LDS(pW[it], &Ws[buf][0] + (it * 256 + t) * 8);
      pW[it] += 32;
    }
  };

  f32x4 acc[4][NJ] = {};
  stage(0);
  const int nkt = K >> 5;
  int cur = 0;
  const int swz = ((fq ^ (fr & 3)) << 4);
  for (int kt = 0; kt < nkt; ++kt) {
    __syncthreads();                   // stage(cur) landed; prev reads done
    if (kt + 1 < nkt) stage(cur ^ 1);
    const char* Al = (const char*)&As[cur][0];
    const char* Wl = (const char*)&Ws[cur][0];
    bf16x8 af[4], wf[NJ];
#pragma unroll
    for (int i = 0; i < 4; ++i)
      af[i] = *(const bf16x8*)(Al + (wr * 64 + i * 16 + fr) * 64 + swz);
#pragma unroll
    for (int j = 0; j < NJ; ++j)
      wf[j] = *(const bf16x8*)(Wl + (wc * WN + j * 16 + fr) * 64 + swz);
#pragma unroll
    for (int i = 0; i < 4; ++i)
#pragma unroll
      for (int j = 0; j < NJ; ++j)
        acc[i][j] = mfma16(af[i], wf[j], acc[i][j]);
    cur ^= 1;
  }

  if (MODE == 2) {
#pragma unroll
    for (int i = 0; i < 4; ++i) {
#pragma unroll
      for (int r = 0; r < 4; ++r) {
        const int m = bm * 128 + wr * 64 + i * 16 + fq * 4 + r;
        if (m < M_TOT) {
          const int b = m / KEEP, jj = m - b * KEEP;
          const int s = idx[b * KEEP + jj];
          float* rp = resid + ((size_t)(b * S_ + s)) * D_ + bn * BN + wc * WN + fr;
          const float* gp = gate + bn * BN + wc * WN + fr;
          const float* bp = bias + bn * BN + wc * WN + fr;
#pragma unroll
          for (int j = 0; j < NJ; ++j)
            rp[j * 16] += gp[j * 16] * (acc[i][j][r] + bp[j * 16]);
        }
      }
    }
  } else {
#pragma unroll
    for (int i = 0; i < 4; ++i) {
#pragma unroll
      for (int j = 0; j < NJ; ++j) {
#pragma unroll
        for (int r = 0; r < 4; ++r) {
          const int m = bm * 128 + wr * 64 + i * 16 + fq * 4 + r;
          const int n = bn * BN + wc * WN + j * 16 + fr;
          float v = acc[i][j][r] + bias[n];
          if (MODE == 0) {
            if (n < D_) v *= QSCALE;
            Cbf[(size_t)m * N + n] = (bf16)v;
          } else {
            float gl = 0.5f * v * (1.f + erff(v * 0.70710678118654752f));
            Cbf[(size_t)m * N + n] = (bf16)gl;
          }
        }
      }
    }
  }
}

// ---------------- flash attention: swapped-QK^T, in-register softmax ---------
// XCD-contiguous 1D grid + hoisted V tr-reads (round-11 config).
__global__ __launch_bounds__(256) void k_attn(const bf16* __restrict__ qkv,
                                              bf16* __restrict__ out)
{
  __shared__ bf16 Klds[2][64 * 64];
  __shared__ bf16 Vlds[2][64 * 64];

  const int t = threadIdx.x;
  const int lane = t & 63, w = t >> 6;
  const int fr = lane & 15, fq = lane >> 4;

  const int orig = blockIdx.x;
  const int wgid = (orig & 7) * 184 + (orig >> 3);
  const int qt = wgid % QT64;
  const int hb = wgid / QT64;
  const int h = hb & 15, b = hb >> 4;

  const size_t rowbase = (size_t)b * KEEP;
  const size_t RS = 3 * D_;
  const bf16* kbase = qkv + rowbase * RS + D_ + h * 64;
  const bf16* vbase = qkv + rowbase * RS + 2 * D_ + h * 64;

  const int wq0 = qt * 64 + w * 16;
  const int qrow = min(wq0 + fr, KEEP - 1);
  const bf16* qp = qkv + (rowbase + qrow) * RS + h * 64 + fq * 8;
  const bf16x8 qf0 = *(const bf16x8*)qp;          // Q as B-operand, d<32
  const bf16x8 qf1 = *(const bf16x8*)(qp + 32);   // d>=32

  f32x4 o[4] = {};
  float mrow = -INFINITY, lrow = 0.f;

  const int p0 = t, p1 = 256 + t;
  auto kaddr = [&](int p, int kv) {
    const int row = p >> 3, c8p = p & 7;
    const int c8 = c8p ^ ((row & 7) ^ (row >> 3));
    const int gr = min(kv + row, KEEP - 1);
    return kbase + (size_t)gr * RS + c8 * 8;
  };
  auto vaddr = [&](int p, int kv) {
    const int db = p >> 7, ksub = (p >> 3) & 15, jr = (p >> 1) & 3,
              c8lo = p & 1;
    const int vrow = ksub * 4 + jr, vc8 = db * 2 + c8lo;
    const int gr = min(kv + vrow, KEEP - 1);
    return vbase + (size_t)gr * RS + vc8 * 8;
  };
  const bf16* kp0 = kaddr(p0, 0);
  const bf16* kp1 = kaddr(p1, 0);
  const bf16* vp0 = vaddr(p0, 0);
  const bf16* vp1 = vaddr(p1, 0);

  auto stage_fast = [&](int buf) {
    GLOAD_LDS(kp0, &Klds[buf][0] + p0 * 8);
    GLOAD_LDS(kp1, &Klds[buf][0] + p1 * 8);
    GLOAD_LDS(vp0, &Vlds[buf][0] + p0 * 8);
    GLOAD_LDS(vp1, &Vlds[buf][0] + p1 * 8);
    kp0 += 64 * RS; kp1 += 64 * RS; vp0 += 64 * RS; vp1 += 64 * RS;
  };
  auto stage_last = [&](int buf, int kv) {
    GLOAD_LDS(kaddr(p0, kv), &Klds[buf][0] + p0 * 8);
    GLOAD_LDS(kaddr(p1, kv), &Klds[buf][0] + p1 * 8);
    GLOAD_LDS(vaddr(p0, kv), &Vlds[buf][0] + p0 * 8);
    GLOAD_LDS(vaddr(p1, kv), &Vlds[buf][0] + p1 * 8);
  };

  stage_fast(0);
  int cur = 0;

  const unsigned vbase_lds0 =
      (unsigned)(size_t)(__attribute__((address_space(3))) bf16*)&Vlds[0][0];
  const unsigned vbase_lds1 =
      (unsigned)(size_t)(__attribute__((address_space(3))) bf16*)&Vlds[1][0];

  for (int ti = 0; ti < NKV; ++ti) {
    const int kv = ti * 64;
    __syncthreads();
    if (ti < NKV - 2) stage_fast(cur ^ 1);
    else if (ti == NKV - 2) stage_last(cur ^ 1, kv + 64);

    const char* Kl = (const char*)&Klds[cur][0];

    f32x4 sc[4];
    __builtin_amdgcn_s_setprio(1);
#pragma unroll
    for (int f = 0; f < 4; ++f) {
      const int row = ((f >> 1) << 5) + ((fr >> 2) << 3) + ((f & 1) << 1) +
                      (fr & 1) + (((fr >> 1) & 1) << 2);
      const int swz = (row & 7) ^ (row >> 3);
      const bf16x8 kf0 = *(const bf16x8*)(Kl + row * 128 + ((fq ^ swz) << 4));
      const bf16x8 kf1 =
          *(const bf16x8*)(Kl + row * 128 + (((fq ^ 4) ^ swz) << 4));
      f32x4 s = {0.f, 0.f, 0.f, 0.f};
      s = mfma16(kf0, qf0, s);
      s = mfma16(kf1, qf1, s);
      sc[f] = s;
    }
    __builtin_amdgcn_s_setprio(0);

    // issue ALL V tr-reads now (no wait): overlap the softmax VALU
    const unsigned vb =
        (cur ? vbase_lds1 : vbase_lds0) + ((unsigned)fq << 7);
    bf16x4 v0[8], v1[8];
    asm volatile(
        "ds_read_b64_tr_b16 %0, %8 offset:0\n\t"
        "ds_read_b64_tr_b16 %1, %8 offset:128\n\t"
        "ds_read_b64_tr_b16 %2, %8 offset:2048\n\t"
        "ds_read_b64_tr_b16 %3, %8 offset:2176\n\t"
        "ds_read_b64_tr_b16 %4, %8 offset:4096\n\t"
        "ds_read_b64_tr_b16 %5, %8 offset:4224\n\t"
        "ds_read_b64_tr_b16 %6, %8 offset:6144\n\t"
        "ds_read_b64_tr_b16 %7, %8 offset:6272"
        : "=&v"(v0[0]), "=&v"(v0[1]), "=&v"(v0[2]), "=&v"(v0[3]),
          "=&v"(v0[4]), "=&v"(v0[5]), "=&v"(v0[6]), "=&v"(v0[7])
        : "v"(vb));
    asm volatile(
        "ds_read_b64_tr_b16 %0, %8 offset:1024\n\t"
        "ds_read_b64_tr_b16 %1, %8 offset:1152\n\t"
        "ds_read_b64_tr_b16 %2, %8 offset:3072\n\t"
        "ds_read_b64_tr_b16 %3, %8 offset:3200\n\t"
        "ds_read_b64_tr_b16 %4, %8 offset:5120\n\t"
        "ds_read_b64_tr_b16 %5, %8 offset:5248\n\t"
        "ds_read_b64_tr_b16 %6, %8 offset:7168\n\t"
        "ds_read_b64_tr_b16 %7, %8 offset:7296"
        : "=&v"(v1[0]), "=&v"(v1[1]), "=&v"(v1[2]), "=&v"(v1[3]),
          "=&v"(v1[4]), "=&v"(v1[5]), "=&v"(v1[6]), "=&v"(v1[7])
        : "v"(vb));

    if (ti == NKV - 1) {
#pragma unroll
      for (int f = 0; f < 4; ++f)
#pragma unroll
        for (int r = 0; r < 4; ++r) {
          const int kl = ((f >> 1) << 5) + (fq << 3) + ((f & 1) << 1) +
                         (r & 1) + ((r >> 1) << 2);
          if (kv + kl >= KEEP) sc[f][r] = -INFINITY;
        }
    }
    float m0 = fmaxf(fmaxf(sc[0][0], sc[0][1]), sc[0][2]);
    float m1 = fmaxf(fmaxf(sc[0][3], sc[1][0]), sc[1][1]);
    float m2 = fmaxf(fmaxf(sc[1][2], sc[1][3]), sc[2][0]);
    float m3 = fmaxf(fmaxf(sc[2][1], sc[2][2]), sc[2][3]);
    float m4 = fmaxf(fmaxf(sc[3][0], sc[3][1]), sc[3][2]);
    float mx = fmaxf(fmaxf(m0, m1), m2);
    mx = fmaxf(fmaxf(mx, m3), fmaxf(m4, sc[3][3]));
    mx = fmaxf(mx, __shfl_xor(mx, 16));
    mx = fmaxf(mx, __shfl_xor(mx, 32));

    const bool noresc = __all(mx <= mrow + 8.f);
    const float mnew = noresc ? mrow : fmaxf(mrow, mx);
    float ps = 0.f;
    bf16 pe[4][4];
#pragma unroll
    for (int f = 0; f < 4; ++f)
#pragma unroll
      for (int r = 0; r < 4; ++r) {
        const float pv = exp2f(sc[f][r] - mnew);
        ps += pv;
        pe[f][r] = (bf16)pv;
      }
    ps += __shfl_xor(ps, 16);
    ps += __shfl_xor(ps, 32);
    if (!noresc) {
      const float fac = exp2f(mrow - mnew);
      lrow *= fac;
#pragma unroll
      for (int db = 0; db < 4; ++db) {
        o[db][0] *= fac; o[db][1] *= fac; o[db][2] *= fac; o[db][3] *= fac;
      }
      mrow = mnew;
    }
    lrow += ps;

    const bf16x8 pb[2] = {
        {pe[0][0], pe[0][1], pe[1][0], pe[1][1],
         pe[0][2], pe[0][3], pe[1][2], pe[1][3]},
        {pe[2][0], pe[2][1], pe[3][0], pe[3][1],
         pe[2][2], pe[2][3], pe[3][2], pe[3][3]}};

    asm volatile("s_waitcnt lgkmcnt(0)" ::: "memory");
    __builtin_amdgcn_sched_barrier(0);

    const bf16x8 vf00 = __builtin_shufflevector(v0[0], v0[1], 0,1,2,3,4,5,6,7);
    const bf16x8 vf01 = __builtin_shufflevector(v0[2], v0[3], 0,1,2,3,4,5,6,7);
    const bf16x8 vf02 = __builtin_shufflevector(v0[4], v0[5], 0,1,2,3,4,5,6,7);
    const bf16x8 vf03 = __builtin_shufflevector(v0[6], v0[7], 0,1,2,3,4,5,6,7);
    const bf16x8 vf10 = __builtin_shufflevector(v1[0], v1[1], 0,1,2,3,4,5,6,7);
    const bf16x8 vf11 = __builtin_shufflevector(v1[2], v1[3], 0,1,2,3,4,5,6,7);
    const bf16x8 vf12 = __builtin_shufflevector(v1[4], v1[5], 0,1,2,3,4,5,6,7);
    const bf16x8 vf13 = __builtin_shufflevector(v1[6], v1[7], 0,1,2,3,4,5,6,7);
    __builtin_amdgcn_s_setprio(1);
    o[0] = mfma16(vf00, pb[0], o[0]);
    o[1] = mfma16(vf01, pb[0], o[1]);
    o[2] = mfma16(vf02, pb[0], o[2]);
    o[3] = mfma16(vf03, pb[0], o[3]);
    o[0] = mfma16(vf10, pb[1], o[0]);
    o[1] = mfma16(vf11, pb[1], o[1]);
    o[2] = mfma16(vf12, pb[1], o[2]);
    o[3] = mfma16(vf13, pb[1], o[3]);
    __builtin_amdgcn_s_setprio(0);
    cur ^= 1;
  }

  const int q = wq0 + fr;
  if (q < KEEP) {
    const float inv = 1.f / lrow;
#pragma unroll
    for (int db = 0; db < 4; ++db) {
      bf16x4 wv = {(bf16)(o[db][0] * inv), (bf16)(o[db][1] * inv),
                   (bf16)(o[db][2] * inv), (bf16)(o[db][3] * inv)};
      *(bf16x4*)(out + (rowbase + q) * (size_t)D_ + h * 64 + db * 16 + fq * 4) =
          wv;
    }
  }
}

// ----------------------------------------------------------------------------
extern "C" void kernel_launch(void* const* d_in, const int* in_sizes, int n_in,
                              void* d_out, int out_size, void* d_ws, size_t ws_size,
                              hipStream_t stream)
{
  (void)in_sizes; (void)n_in; (void)out_size; (void)ws_size;
  const float* x      = (const float*)d_in[0];
  const float* t_emb  = (const float*)d_in[1];
  const float* tr_w1  = (const float*)d_in[2];
  const float* tr_b1  = (const float*)d_in[3];
  const float* tr_w2  = (const float*)d_in[4];
  const float* tr_b2  = (const float*)d_in[5];
  const float* ln1_w  = (const float*)d_in[6];
  const float* ln1_b  = (const float*)d_in[7];
  const float* ln2_w  = (const float*)d_in[8];
  const float* ln2_b  = (const float*)d_in[9];
  const float* in_w   = (const float*)d_in[10];
  const float* in_b   = (const float*)d_in[11];
  const float* out_w  = (const float*)d_in[12];
  const float* out_b  = (const float*)d_in[13];
  const float* f1_w   = (const float*)d_in[14];
  const float* f1_b   = (const float*)d_in[15];
  const float* f2_w   = (const float*)d_in[16];
  const float* f2_b   = (const float*)d_in[17];
  const float* gate_a = (const float*)d_in[18];
  const float* gate_f = (const float*)d_in[19];

  char* ws = (char*)d_ws;
  size_t off = 0;
  auto alloc = [&](size_t bytes) -> char* {
    char* p = ws + off;
    off = (off + bytes + 255) & ~(size_t)255;
    return p;
  };
  double* imp  = (double*)alloc((size_t)B_ * S_ * 8);
  double* hid  = (double*)alloc((size_t)B_ * S_ * 32 * 8);
  int* rank    = (int*)alloc((size_t)B_ * S_ * 4);
  int* idx     = (int*)alloc((size_t)B_ * KEEP * 4);
  float* p1    = (float*)alloc((size_t)B_ * 2 * D_ * 4);
  float* p2    = (float*)alloc((size_t)B_ * 2 * D_ * 4);
  bf16* w_in   = (bf16*)alloc((size_t)3 * D_ * D_ * 2);
  bf16* w_out  = (bf16*)alloc((size_t)D_ * D_ * 2);
  bf16* w_f1   = (bf16*)alloc((size_t)DFF_ * D_ * 2);
  bf16* w_f2   = (bf16*)alloc((size_t)D_ * DFF_ * 2);
  bf16* h_bf   = (bf16*)alloc((size_t)MPAD * D_ * 2);
  bf16* big    = (bf16*)alloc((size_t)MPAD * (3 * D_ + D_) * 2);
  bf16* qkv    = big;
  bf16* attn   = big + (size_t)MPAD * 3 * D_;
  bf16* ffn1   = big;   // overlays qkv+attn (both dead by then)

  k_prep<<<8704, 256, 0, stream>>>(
      x, tr_w1, hid,
      in_w, out_w, f1_w, f2_w, w_in, w_out, w_f1, w_f2,
      (float*)d_out,
      t_emb, ln1_w, ln1_b, p1, ln2_w, ln2_b, p2);
  k_imptail<<<B_ * S_ / 256, 256, 0, stream>>>(hid, tr_b1, tr_w2, tr_b2, imp);
  k_rank<<<B_ * 32, 256, 0, stream>>>(imp, rank);
  k_compact<<<B_, 256, 0, stream>>>(rank, idx);

  k_adaln<<<MPAD, 256, 0, stream>>>(x, idx, p1, h_bf);
  k_gemm<128, 0><<<46 * 24, 256, 0, stream>>>(
      h_bf, w_in, in_b, qkv, nullptr, nullptr, nullptr, 3 * D_, D_, 24);
  k_attn<<<QT64 * H_ * B_, 256, 0, stream>>>(qkv, attn);
  k_gemm<64, 2><<<46 * 16, 256, 0, stream>>>(
      attn, w_out, out_b, nullptr, gate_a, idx, (float*)d_out, D_, D_, 16);
  k_adaln<<<MPAD, 256, 0, stream>>>((const float*)d_out, idx, p2, h_bf);
  k_gemm<128, 1><<<46 * 32, 256, 0, stream>>>(
      h_bf, w_f1, f1_b, ffn1, nullptr, nullptr, nullptr, DFF_, D_, 32);
  k_gemm<64, 2><<<46 * 16, 256, 0, stream>>>(
      ffn1, w_f2, f2_b, nullptr, gate_f, idx, (float*)d_out, D_, DFF_, 16);
}

// Round 17
// 421.513 us; speedup vs baseline: 1.0570x; 1.0570x over previous
//
#include <hip/hip_runtime.h>
#include <hip/hip_bf16.h>
#include <cmath>
#include <cstdint>

typedef __bf16 bf16;
typedef __bf16 bf16x8 __attribute__((ext_vector_type(8)));
typedef __bf16 bf16x4 __attribute__((ext_vector_type(4)));
typedef float  f32x4  __attribute__((ext_vector_type(4)));

constexpr int B_   = 4;
constexpr int S_   = 2048;
constexpr int D_   = 1024;
constexpr int H_   = 16;
constexpr int DFF_ = 4096;
constexpr int TD_  = 256;
constexpr int KEEP = 1433;              // int(2048*0.7)
constexpr int M_TOT = B_ * KEEP;        // 5732
constexpr int MPAD  = 5888;             // 46*128
constexpr int QT64  = (KEEP + 63) / 64; // 23
constexpr int NKV   = (KEEP + 63) / 64; // 23
constexpr float EPS = 1e-5f;
// 1/sqrt(64) * log2(e): folded into Q in the QKV epilogue; attn uses exp2.
constexpr float QSCALE = 0.18033688011112042f;

__device__ __forceinline__ f32x4 mfma16(bf16x8 a, bf16x8 b, f32x4 c) {
  return __builtin_amdgcn_mfma_f32_16x16x32_bf16(a, b, c, 0, 0, 0);
}

#define GLOAD_LDS(gp, lp)                                                     \
  __builtin_amdgcn_global_load_lds(                                           \
      (const __attribute__((address_space(1))) void*)(gp),                    \
      (__attribute__((address_space(3))) void*)(lp), 16, 0, 0)

// ---------------- fused prep ------------------------------------------------
// [0,2048)     importance GEMV (u0 slow index -> same-XCD x reuse);
//              reduction via LDS transpose (replaces 384 swizzle-ops/wave
//              with ~72 -> LDS pipe decongested)
// [2048,3584)  fp32->bf16 weight casts, 8 float4/thread
// [3584,4608)  d_out = x copy, 8 float4/thread
// [4608,8704)  cond projections x2
__global__ __launch_bounds__(256) void k_prep(
    const float* __restrict__ x, const float* __restrict__ tr_w1,
    double* __restrict__ hidden,
    const float* __restrict__ in_w, const float* __restrict__ out_w,
    const float* __restrict__ f1_w, const float* __restrict__ f2_w,
    bf16* __restrict__ w_in, bf16* __restrict__ w_out,
    bf16* __restrict__ w_f1, bf16* __restrict__ w_f2,
    float* __restrict__ dout,
    const float* __restrict__ temb,
    const float* __restrict__ ln1_w, const float* __restrict__ ln1_b,
    float* __restrict__ p1,
    const float* __restrict__ ln2_w, const float* __restrict__ ln2_b,
    float* __restrict__ p2)
{
  __shared__ double sred[4][64][17];   // per-wave [src lane][16 accs + pad]
  const int bid = blockIdx.x;
  if (bid < 2048) {
    // ---- importance GEMV: 4 tokens x 8 units per wave, fp64 accumulate
    const int lane = threadIdx.x & 63, w = threadIdx.x >> 6;
    const int tok0 = (bid & 511) * 16 + w * 4;
    const int u0 = (bid >> 9) * 8;
    const float* xb = x + (size_t)tok0 * D_ + lane * 4;
    const float* wb = tr_w1 + (size_t)u0 * D_ + lane * 4;
    double acc[4][8] = {};
#pragma unroll 2
    for (int c = 0; c < D_; c += 256) {
      float4 xv[4], wv[8];
#pragma unroll
      for (int i = 0; i < 4; ++i)
        xv[i] = *(const float4*)(xb + (size_t)i * D_ + c);
#pragma unroll
      for (int u = 0; u < 8; ++u)
        wv[u] = *(const float4*)(wb + (size_t)u * D_ + c);
#pragma unroll
      for (int i = 0; i < 4; ++i)
#pragma unroll
        for (int u = 0; u < 8; ++u) {
          acc[i][u] += (double)xv[i].x * (double)wv[u].x;
          acc[i][u] += (double)xv[i].y * (double)wv[u].y;
          acc[i][u] += (double)xv[i].z * (double)wv[u].z;
          acc[i][u] += (double)xv[i].w * (double)wv[u].w;
        }
    }
    // ---- LDS-transpose reduction: 2 batches of 16 accs.
    double* my = &sred[w][0][0];
#pragma unroll
    for (int bt = 0; bt < 2; ++bt) {
#pragma unroll
      for (int a = 0; a < 16; ++a)
        my[lane * 17 + a] = acc[2 * bt + (a >> 3)][a & 7];
      asm volatile("s_waitcnt lgkmcnt(0)" ::: "memory");
      __builtin_amdgcn_sched_barrier(0);
      const int a = lane >> 2, sl = lane & 3;
      const double* rp = my + (sl * 16) * 17 + a;
      double s0 = rp[0]        + rp[17];
      double s1 = rp[2  * 17]  + rp[3  * 17];
      double s2 = rp[4  * 17]  + rp[5  * 17];
      double s3 = rp[6  * 17]  + rp[7  * 17];
      s0 += rp[8  * 17]; s1 += rp[9  * 17];
      s2 += rp[10 * 17]; s3 += rp[11 * 17];
      s0 += rp[12 * 17]; s1 += rp[13 * 17];
      s2 += rp[14 * 17]; s3 += rp[15 * 17];
      double s = (s0 + s1) + (s2 + s3);
      s += __shfl_xor(s, 1);
      s += __shfl_xor(s, 2);
      if (sl == 0)
        hidden[(size_t)(tok0 + 2 * bt + (a >> 3)) * 32 + u0 + (a & 7)] = s;
      asm volatile("s_waitcnt lgkmcnt(0)" ::: "memory");
      __builtin_amdgcn_sched_barrier(0);
    }
  } else if (bid < 3584) {
    // ---- fp32 -> bf16 weight casts: 8 float4 per thread
    const int base = (bid - 2048) * 2048 + threadIdx.x;
#pragma unroll
    for (int k2 = 0; k2 < 8; ++k2) {
      const int g = base + k2 * 256;
      const float* src; bf16* dst; int off;
      if (g < 786432)       { src = in_w;  dst = w_in;  off = g; }
      else if (g < 1048576) { src = out_w; dst = w_out; off = g - 786432; }
      else if (g < 2097152) { src = f1_w;  dst = w_f1;  off = g - 1048576; }
      else                  { src = f2_w;  dst = w_f2;  off = g - 2097152; }
      float4 v = ((const float4*)src)[off];
      bf16x4 o = {(bf16)v.x, (bf16)v.y, (bf16)v.z, (bf16)v.w};
      ((bf16x4*)dst)[off] = o;
    }
  } else if (bid < 4608) {
    // ---- d_out = x: 8 float4 per thread
    const int base = (bid - 3584) * 2048 + threadIdx.x;
    float4 v[8];
#pragma unroll
    for (int k2 = 0; k2 < 8; ++k2) v[k2] = ((const float4*)x)[base + k2 * 256];
#pragma unroll
    for (int k2 = 0; k2 < 8; ++k2) ((float4*)dout)[base + k2 * 256] = v[k2];
  } else {
    // ---- cond projections
    int gw = (int)(((bid - 4608) * 256 + threadIdx.x) >> 6);
    const int lane = threadIdx.x & 63;
    const float* W = ln1_w; const float* bias = ln1_b; float* p = p1;
    if (gw >= 8192) { gw -= 8192; W = ln2_w; bias = ln2_b; p = p2; }
    const int b = gw >> 11;
    const int row = gw & 2047;
    const float* te = temb + (size_t)b * TD_;
    const float* wr = W + (size_t)row * TD_;
    float acc = 0.f;
    for (int i = lane; i < TD_; i += 64) {
      float c = te[i];
      acc += (c / (1.f + __expf(-c))) * wr[i];
    }
    for (int o = 32; o > 0; o >>= 1) acc += __shfl_down(acc, o);
    if (lane == 0) p[(size_t)b * 2 * D_ + row] = acc + bias[row];
  }
}

// ---------------- importance tail: imp = silu(hidden + b1) . w2 + b2 --------
__global__ __launch_bounds__(256) void k_imptail(
    const double* __restrict__ hidden, const float* __restrict__ b1,
    const float* __restrict__ w2, const float* __restrict__ b2,
    double* __restrict__ imp)
{
  const int tok = blockIdx.x * 256 + threadIdx.x;
  const double* hp = hidden + (size_t)tok * 32;
  double r = 0.0;
#pragma unroll
  for (int u = 0; u < 32; ++u) {
    double s = hp[u] + (double)b1[u];
    double sv = s / (1.0 + exp(-s));
    r += sv * (double)w2[u];
  }
  imp[tok] = r + (double)b2[0];
}

// ---------------- rank: #(greater) or (equal && earlier) ---------------------
__global__ __launch_bounds__(256) void k_rank(const double* __restrict__ imp,
                                              int* __restrict__ rank)
{
  const int b = blockIdx.x >> 5;
  const int seg = blockIdx.x & 31;     // 64 tokens per block
  __shared__ double vals[S_];
  const double* ib = imp + (size_t)b * S_;
  for (int i = threadIdx.x; i < S_ / 2; i += 256)
    ((double2*)vals)[i] = ((const double2*)ib)[i];
  __syncthreads();
  const int tl = threadIdx.x >> 2;     // token within segment
  const int part = threadIdx.x & 3;    // quarter of the scan
  const int s = seg * 64 + tl;
  const double v = vals[s];
  int cnt = 0;
  for (int j = part * 512; j < (part + 1) * 512; ++j) {
    double u = vals[j];
    cnt += (u > v) || (u == v && j < s);
  }
  cnt += __shfl_xor(cnt, 1);
  cnt += __shfl_xor(cnt, 2);
  if (part == 0) rank[b * S_ + s] = cnt;
}

// ---------------- compact kept indices (ascending) ---------------------------
__global__ __launch_bounds__(256) void k_compact(const int* __restrict__ rank,
                                                 int* __restrict__ idx)
{
  const int b = blockIdx.x;
  __shared__ int wcnt[4];
  __shared__ int base_s;
  if (threadIdx.x == 0) base_s = 0;
  __syncthreads();
  const int t = threadIdx.x, lane = t & 63, w = t >> 6;
  for (int c = 0; c < S_ / 256; ++c) {
    const int s = c * 256 + t;
    const bool kept = rank[b * S_ + s] < KEEP;
    unsigned long long m = __ballot(kept);
    int piw = __popcll(m & ((1ull << lane) - 1ull));
    if (lane == 0) wcnt[w] = __popcll(m);
    __syncthreads();
    int off = base_s;
    for (int i = 0; i < w; ++i) off += wcnt[i];
    if (kept) idx[b * KEEP + off + piw] = s;
    __syncthreads();
    if (t == 0) base_s += wcnt[0] + wcnt[1] + wcnt[2] + wcnt[3];
    __syncthreads();
  }
}

// ---------------- gather + adaLN -> bf16 -------------------------------------
__global__ __launch_bounds__(256) void k_adaln(
    const float* __restrict__ xsrc, const int* __restrict__ idx,
    const float* __restrict__ p, bf16* __restrict__ hout)
{
  const int r = blockIdx.x, t = threadIdx.x;
  bf16* orow = hout + (size_t)r * D_;
  if (r >= M_TOT) {
    bf16x4 z = {(bf16)0.f, (bf16)0.f, (bf16)0.f, (bf16)0.f};
    ((bf16x4*)orow)[t] = z;
    return;
  }
  const int b = r / KEEP, j = r - b * KEEP;
  const int s = idx[b * KEEP + j];
  const float* xr = xsrc + ((size_t)(b * S_ + s)) * D_;
  float4 v = ((const float4*)xr)[t];
  __shared__ float red[8];
  float sum = v.x + v.y + v.z + v.w;
  for (int o = 32; o > 0; o >>= 1) sum += __shfl_down(sum, o);
  const int lane = t & 63, w = t >> 6;
  if (lane == 0) red[w] = sum;
  __syncthreads();
  const float mu = (red[0] + red[1] + red[2] + red[3]) * (1.f / D_);
  const float dx = v.x - mu, dy = v.y - mu, dz = v.z - mu, dw = v.w - mu;
  float vs = dx * dx + dy * dy + dz * dz + dw * dw;
  for (int o = 32; o > 0; o >>= 1) vs += __shfl_down(vs, o);
  if (lane == 0) red[4 + w] = vs;
  __syncthreads();
  const float rstd = rsqrtf((red[4] + red[5] + red[6] + red[7]) * (1.f / D_) + EPS);
  const float* gp = p + (size_t)b * 2 * D_;
  float4 g  = ((const float4*)gp)[t];
  float4 be = ((const float4*)(gp + D_))[t];
  bf16x4 o;
  o[0] = (bf16)(dx * rstd * (1.f + g.x) + be.x);
  o[1] = (bf16)(dy * rstd * (1.f + g.y) + be.y);
  o[2] = (bf16)(dz * rstd * (1.f + g.z) + be.z);
  o[3] = (bf16)(dw * rstd * (1.f + g.w) + be.w);
  ((bf16x4*)orow)[t] = o;
}

// ---------------- GEMM 128xBN, BK=32 (32KB LDS, 3 blk/CU) -------------------
// 2-phase dbuf, 2-bit chunk swizzle, hoisted staging, bijective XCD remap.
// MODE 0: bias (+QSCALE on Q third) -> bf16. MODE 1: bias+gelu -> bf16.
// MODE 2: bias, then resid[row(m)][n] += gate[n]*v (gathered residual).
template <int BN, int MODE>
__global__ __launch_bounds__(256) void k_gemm(
    const bf16* __restrict__ A, const bf16* __restrict__ W,
    const float* __restrict__ bias, bf16* __restrict__ Cbf,
    const float* __restrict__ gate, const int* __restrict__ idx,
    float* __restrict__ resid, int N, int K, int gn)
{
  constexpr int WN = BN / 2;      // per-wave N span
  constexpr int NJ = WN / 16;     // N fragments per wave
  constexpr int WIT = BN / 64;    // W staging rounds (BN*32 / 2048)
  __shared__ bf16 As[2][128 * 32];
  __shared__ bf16 Ws[2][BN * 32];
  const int t = threadIdx.x, lane = t & 63;
  const int w = t >> 6, wr = w >> 1, wc = w & 1;
  const int fr = lane & 15, fq = lane >> 4;

  // bijective XCD-contiguous remap (m204)
  const int nwg = gridDim.x, orig = blockIdx.x;
  const int q8 = nwg >> 3, r8 = nwg & 7;
  const int xc = orig & 7, pos = orig >> 3;
  const int wgid = (xc < r8 ? xc * (q8 + 1) : r8 * (q8 + 1) + (xc - r8) * q8) + pos;
  const int bm = wgid / gn, bn = wgid - bm * gn;

  const bf16* Ab = A + (size_t)bm * 128 * K;
  const bf16* Wb = W + (size_t)bn * BN * K;

  const bf16* pA[2];
  const bf16* pW[WIT];
#pragma unroll
  for (int it = 0; it < 2; ++it) {
    const int e = it * 256 + t;
    const int row = e >> 2, pc = e & 3;
    const int lc = pc ^ (row & 3);
    pA[it] = Ab + (size_t)row * K + lc * 8;
  }
#pragma unroll
  for (int it = 0; it < WIT; ++it) {
    const int e = it * 256 + t;
    const int row = e >> 2, pc = e & 3;
    const int lc = pc ^ (row & 3);
    pW[it] = Wb + (size_t)row * K + lc * 8;
  }

  auto stage = [&](int buf) {
#pragma unroll
    for (int it = 0; it < 2; ++it) {
      GLOAD_LDS(pA[it], &As[buf][0] + (it * 256 + t) * 8);
      pA[it] += 32;
    }
#pragma unroll
    for (int it = 0; it < WIT; ++it) {
      GLOAD_LDS(pW[it], &Ws[buf][0] + (it * 256 + t) * 8);
      pW[it] += 32;
    }
  };

  f32x4 acc[4][NJ] = {};
  stage(0);
  const int nkt = K >> 5;
  int cur = 0;
  const int swz = ((fq ^ (fr & 3)) << 4);
  for (int kt = 0; kt < nkt; ++kt) {
    __syncthreads();                   // stage(cur) landed; prev reads done
    if (kt + 1 < nkt) stage(cur ^ 1);
    const char* Al = (const char*)&As[cur][0];
    const char* Wl = (const char*)&Ws[cur][0];
    bf16x8 af[4], wf[NJ];
#pragma unroll
    for (int i = 0; i < 4; ++i)
      af[i] = *(const bf16x8*)(Al + (wr * 64 + i * 16 + fr) * 64 + swz);
#pragma unroll
    for (int j = 0; j < NJ; ++j)
      wf[j] = *(const bf16x8*)(Wl + (wc * WN + j * 16 + fr) * 64 + swz);
#pragma unroll
    for (int i = 0; i < 4; ++i)
#pragma unroll
      for (int j = 0; j < NJ; ++j)
        acc[i][j] = mfma16(af[i], wf[j], acc[i][j]);
    cur ^= 1;
  }

  if (MODE == 2) {
#pragma unroll
    for (int i = 0; i < 4; ++i) {
#pragma unroll
      for (int r = 0; r < 4; ++r) {
        const int m = bm * 128 + wr * 64 + i * 16 + fq * 4 + r;
        if (m < M_TOT) {
          const int b = m / KEEP, jj = m - b * KEEP;
          const int s = idx[b * KEEP + jj];
          float* rp = resid + ((size_t)(b * S_ + s)) * D_ + bn * BN + wc * WN + fr;
          const float* gp = gate + bn * BN + wc * WN + fr;
          const float* bp = bias + bn * BN + wc * WN + fr;
#pragma unroll
          for (int j = 0; j < NJ; ++j)
            rp[j * 16] += gp[j * 16] * (acc[i][j][r] + bp[j * 16]);
        }
      }
    }
  } else {
#pragma unroll
    for (int i = 0; i < 4; ++i) {
#pragma unroll
      for (int j = 0; j < NJ; ++j) {
#pragma unroll
        for (int r = 0; r < 4; ++r) {
          const int m = bm * 128 + wr * 64 + i * 16 + fq * 4 + r;
          const int n = bn * BN + wc * WN + j * 16 + fr;
          float v = acc[i][j][r] + bias[n];
          if (MODE == 0) {
            if (n < D_) v *= QSCALE;
            Cbf[(size_t)m * N + n] = (bf16)v;
          } else {
            float gl = 0.5f * v * (1.f + erff(v * 0.70710678118654752f));
            Cbf[(size_t)m * N + n] = (bf16)gl;
          }
        }
      }
    }
  }
}

// ---------------- flash attention: swapped-QK^T, in-register softmax ---------
// XCD-contiguous 1D grid + hoisted V tr-reads (round-11 config).
__global__ __launch_bounds__(256) void k_attn(const bf16* __restrict__ qkv,
                                              bf16* __restrict__ out)
{
  __shared__ bf16 Klds[2][64 * 64];
  __shared__ bf16 Vlds[2][64 * 64];

  const int t = threadIdx.x;
  const int lane = t & 63, w = t >> 6;
  const int fr = lane & 15, fq = lane >> 4;

  const int orig = blockIdx.x;
  const int wgid = (orig & 7) * 184 + (orig >> 3);
  const int qt = wgid % QT64;
  const int hb = wgid / QT64;
  const int h = hb & 15, b = hb >> 4;

  const size_t rowbase = (size_t)b * KEEP;
  const size_t RS = 3 * D_;
  const bf16* kbase = qkv + rowbase * RS + D_ + h * 64;
  const bf16* vbase = qkv + rowbase * RS + 2 * D_ + h * 64;

  const int wq0 = qt * 64 + w * 16;
  const int qrow = min(wq0 + fr, KEEP - 1);
  const bf16* qp = qkv + (rowbase + qrow) * RS + h * 64 + fq * 8;
  const bf16x8 qf0 = *(const bf16x8*)qp;          // Q as B-operand, d<32
  const bf16x8 qf1 = *(const bf16x8*)(qp + 32);   // d>=32

  f32x4 o[4] = {};
  float mrow = -INFINITY, lrow = 0.f;

  const int p0 = t, p1 = 256 + t;
  auto kaddr = [&](int p, int kv) {
    const int row = p >> 3, c8p = p & 7;
    const int c8 = c8p ^ ((row & 7) ^ (row >> 3));
    const int gr = min(kv + row, KEEP - 1);
    return kbase + (size_t)gr * RS + c8 * 8;
  };
  auto vaddr = [&](int p, int kv) {
    const int db = p >> 7, ksub = (p >> 3) & 15, jr = (p >> 1) & 3,
              c8lo = p & 1;
    const int vrow = ksub * 4 + jr, vc8 = db * 2 + c8lo;
    const int gr = min(kv + vrow, KEEP - 1);
    return vbase + (size_t)gr * RS + vc8 * 8;
  };
  const bf16* kp0 = kaddr(p0, 0);
  const bf16* kp1 = kaddr(p1, 0);
  const bf16* vp0 = vaddr(p0, 0);
  const bf16* vp1 = vaddr(p1, 0);

  auto stage_fast = [&](int buf) {
    GLOAD_LDS(kp0, &Klds[buf][0] + p0 * 8);
    GLOAD_LDS(kp1, &Klds[buf][0] + p1 * 8);
    GLOAD_LDS(vp0, &Vlds[buf][0] + p0 * 8);
    GLOAD_LDS(vp1, &Vlds[buf][0] + p1 * 8);
    kp0 += 64 * RS; kp1 += 64 * RS; vp0 += 64 * RS; vp1 += 64 * RS;
  };
  auto stage_last = [&](int buf, int kv) {
    GLOAD_LDS(kaddr(p0, kv), &Klds[buf][0] + p0 * 8);
    GLOAD_LDS(kaddr(p1, kv), &Klds[buf][0] + p1 * 8);
    GLOAD_LDS(vaddr(p0, kv), &Vlds[buf][0] + p0 * 8);
    GLOAD_LDS(vaddr(p1, kv), &Vlds[buf][0] + p1 * 8);
  };

  stage_fast(0);
  int cur = 0;

  const unsigned vbase_lds0 =
      (unsigned)(size_t)(__attribute__((address_space(3))) bf16*)&Vlds[0][0];
  const unsigned vbase_lds1 =
      (unsigned)(size_t)(__attribute__((address_space(3))) bf16*)&Vlds[1][0];

  for (int ti = 0; ti < NKV; ++ti) {
    const int kv = ti * 64;
    __syncthreads();
    if (ti < NKV - 2) stage_fast(cur ^ 1);
    else if (ti == NKV - 2) stage_last(cur ^ 1, kv + 64);

    const char* Kl = (const char*)&Klds[cur][0];

    f32x4 sc[4];
    __builtin_amdgcn_s_setprio(1);
#pragma unroll
    for (int f = 0; f < 4; ++f) {
      const int row = ((f >> 1) << 5) + ((fr >> 2) << 3) + ((f & 1) << 1) +
                      (fr & 1) + (((fr >> 1) & 1) << 2);
      const int swz = (row & 7) ^ (row >> 3);
      const bf16x8 kf0 = *(const bf16x8*)(Kl + row * 128 + ((fq ^ swz) << 4));
      const bf16x8 kf1 =
          *(const bf16x8*)(Kl + row * 128 + (((fq ^ 4) ^ swz) << 4));
      f32x4 s = {0.f, 0.f, 0.f, 0.f};
      s = mfma16(kf0, qf0, s);
      s = mfma16(kf1, qf1, s);
      sc[f] = s;
    }
    __builtin_amdgcn_s_setprio(0);

    // issue ALL V tr-reads now (no wait): overlap the softmax VALU
    const unsigned vb =
        (cur ? vbase_lds1 : vbase_lds0) + ((unsigned)fq << 7);
    bf16x4 v0[8], v1[8];
    asm volatile(
        "ds_read_b64_tr_b16 %0, %8 offset:0\n\t"
        "ds_read_b64_tr_b16 %1, %8 offset:128\n\t"
        "ds_read_b64_tr_b16 %2, %8 offset:2048\n\t"
        "ds_read_b64_tr_b16 %3, %8 offset:2176\n\t"
        "ds_read_b64_tr_b16 %4, %8 offset:4096\n\t"
        "ds_read_b64_tr_b16 %5, %8 offset:4224\n\t"
        "ds_read_b64_tr_b16 %6, %8 offset:6144\n\t"
        "ds_read_b64_tr_b16 %7, %8 offset:6272"
        : "=&v"(v0[0]), "=&v"(v0[1]), "=&v"(v0[2]), "=&v"(v0[3]),
          "=&v"(v0[4]), "=&v"(v0[5]), "=&v"(v0[6]), "=&v"(v0[7])
        : "v"(vb));
    asm volatile(
        "ds_read_b64_tr_b16 %0, %8 offset:1024\n\t"
        "ds_read_b64_tr_b16 %1, %8 offset:1152\n\t"
        "ds_read_b64_tr_b16 %2, %8 offset:3072\n\t"
        "ds_read_b64_tr_b16 %3, %8 offset:3200\n\t"
        "ds_read_b64_tr_b16 %4, %8 offset:5120\n\t"
        "ds_read_b64_tr_b16 %5, %8 offset:5248\n\t"
        "ds_read_b64_tr_b16 %6, %8 offset:7168\n\t"
        "ds_read_b64_tr_b16 %7, %8 offset:7296"
        : "=&v"(v1[0]), "=&v"(v1[1]), "=&v"(v1[2]), "=&v"(v1[3]),
          "=&v"(v1[4]), "=&v"(v1[5]), "=&v"(v1[6]), "=&v"(v1[7])
        : "v"(vb));

    if (ti == NKV - 1) {
#pragma unroll
      for (int f = 0; f < 4; ++f)
#pragma unroll
        for (int r = 0; r < 4; ++r) {
          const int kl = ((f >> 1) << 5) + (fq << 3) + ((f & 1) << 1) +
                         (r & 1) + ((r >> 1) << 2);
          if (kv + kl >= KEEP) sc[f][r] = -INFINITY;
        }
    }
    float m0 = fmaxf(fmaxf(sc[0][0], sc[0][1]), sc[0][2]);
    float m1 = fmaxf(fmaxf(sc[0][3], sc[1][0]), sc[1][1]);
    float m2 = fmaxf(fmaxf(sc[1][2], sc[1][3]), sc[2][0]);
    float m3 = fmaxf(fmaxf(sc[2][1], sc[2][2]), sc[2][3]);
    float m4 = fmaxf(fmaxf(sc[3][0], sc[3][1]), sc[3][2]);
    float mx = fmaxf(fmaxf(m0, m1), m2);
    mx = fmaxf(fmaxf(mx, m3), fmaxf(m4, sc[3][3]));
    mx = fmaxf(mx, __shfl_xor(mx, 16));
    mx = fmaxf(mx, __shfl_xor(mx, 32));

    const bool noresc = __all(mx <= mrow + 8.f);
    const float mnew = noresc ? mrow : fmaxf(mrow, mx);
    float ps = 0.f;
    bf16 pe[4][4];
#pragma unroll
    for (int f = 0; f < 4; ++f)
#pragma unroll
      for (int r = 0; r < 4; ++r) {
        const float pv = exp2f(sc[f][r] - mnew);
        ps += pv;
        pe[f][r] = (bf16)pv;
      }
    ps += __shfl_xor(ps, 16);
    ps += __shfl_xor(ps, 32);
    if (!noresc) {
      const float fac = exp2f(mrow - mnew);
      lrow *= fac;
#pragma unroll
      for (int db = 0; db < 4; ++db) {
        o[db][0] *= fac; o[db][1] *= fac; o[db][2] *= fac; o[db][3] *= fac;
      }
      mrow = mnew;
    }
    lrow += ps;

    const bf16x8 pb[2] = {
        {pe[0][0], pe[0][1], pe[1][0], pe[1][1],
         pe[0][2], pe[0][3], pe[1][2], pe[1][3]},
        {pe[2][0], pe[2][1], pe[3][0], pe[3][1],
         pe[2][2], pe[2][3], pe[3][2], pe[3][3]}};

    asm volatile("s_waitcnt lgkmcnt(0)" ::: "memory");
    __builtin_amdgcn_sched_barrier(0);

    const bf16x8 vf00 = __builtin_shufflevector(v0[0], v0[1], 0,1,2,3,4,5,6,7);
    const bf16x8 vf01 = __builtin_shufflevector(v0[2], v0[3], 0,1,2,3,4,5,6,7);
    const bf16x8 vf02 = __builtin_shufflevector(v0[4], v0[5], 0,1,2,3,4,5,6,7);
    const bf16x8 vf03 = __builtin_shufflevector(v0[6], v0[7], 0,1,2,3,4,5,6,7);
    const bf16x8 vf10 = __builtin_shufflevector(v1[0], v1[1], 0,1,2,3,4,5,6,7);
    const bf16x8 vf11 = __builtin_shufflevector(v1[2], v1[3], 0,1,2,3,4,5,6,7);
    const bf16x8 vf12 = __builtin_shufflevector(v1[4], v1[5], 0,1,2,3,4,5,6,7);
    const bf16x8 vf13 = __builtin_shufflevector(v1[6], v1[7], 0,1,2,3,4,5,6,7);
    __builtin_amdgcn_s_setprio(1);
    o[0] = mfma16(vf00, pb[0], o[0]);
    o[1] = mfma16(vf01, pb[0], o[1]);
    o[2] = mfma16(vf02, pb[0], o[2]);
    o[3] = mfma16(vf03, pb[0], o[3]);
    o[0] = mfma16(vf10, pb[1], o[0]);
    o[1] = mfma16(vf11, pb[1], o[1]);
    o[2] = mfma16(vf12, pb[1], o[2]);
    o[3] = mfma16(vf13, pb[1], o[3]);
    __builtin_amdgcn_s_setprio(0);
    cur ^= 1;
  }

  const int q = wq0 + fr;
  if (q < KEEP) {
    const float inv = 1.f / lrow;
#pragma unroll
    for (int db = 0; db < 4; ++db) {
      bf16x4 wv = {(bf16)(o[db][0] * inv), (bf16)(o[db][1] * inv),
                   (bf16)(o[db][2] * inv), (bf16)(o[db][3] * inv)};
      *(bf16x4*)(out + (rowbase + q) * (size_t)D_ + h * 64 + db * 16 + fq * 4) =
          wv;
    }
  }
}

// ----------------------------------------------------------------------------
extern "C" void kernel_launch(void* const* d_in, const int* in_sizes, int n_in,
                              void* d_out, int out_size, void* d_ws, size_t ws_size,
                              hipStream_t stream)
{
  (void)in_sizes; (void)n_in; (void)out_size; (void)ws_size;
  const float* x      = (const float*)d_in[0];
  const float* t_emb  = (const float*)d_in[1];
  const float* tr_w1  = (const float*)d_in[2];
  const float* tr_b1  = (const float*)d_in[3];
  const float* tr_w2  = (const float*)d_in[4];
  const float* tr_b2  = (const float*)d_in[5];
  const float* ln1_w  = (const float*)d_in[6];
  const float* ln1_b  = (const float*)d_in[7];
  const float* ln2_w  = (const float*)d_in[8];
  const float* ln2_b  = (const float*)d_in[9];
  const float* in_w   = (const float*)d_in[10];
  const float* in_b   = (const float*)d_in[11];
  const float* out_w  = (const float*)d_in[12];
  const float* out_b  = (const float*)d_in[13];
  const float* f1_w   = (const float*)d_in[14];
  const float* f1_b   = (const float*)d_in[15];
  const float* f2_w   = (const float*)d_in[16];
  const float* f2_b   = (const float*)d_in[17];
  const float* gate_a = (const float*)d_in[18];
  const float* gate_f = (const float*)d_in[19];

  char* ws = (char*)d_ws;
  size_t off = 0;
  auto alloc = [&](size_t bytes) -> char* {
    char* p = ws + off;
    off = (off + bytes + 255) & ~(size_t)255;
    return p;
  };
  double* imp  = (double*)alloc((size_t)B_ * S_ * 8);
  double* hid  = (double*)alloc((size_t)B_ * S_ * 32 * 8);
  int* rank    = (int*)alloc((size_t)B_ * S_ * 4);
  int* idx     = (int*)alloc((size_t)B_ * KEEP * 4);
  float* p1    = (float*)alloc((size_t)B_ * 2 * D_ * 4);
  float* p2    = (float*)alloc((size_t)B_ * 2 * D_ * 4);
  bf16* w_in   = (bf16*)alloc((size_t)3 * D_ * D_ * 2);
  bf16* w_out  = (bf16*)alloc((size_t)D_ * D_ * 2);
  bf16* w_f1   = (bf16*)alloc((size_t)DFF_ * D_ * 2);
  bf16* w_f2   = (bf16*)alloc((size_t)D_ * DFF_ * 2);
  bf16* h_bf   = (bf16*)alloc((size_t)MPAD * D_ * 2);
  bf16* big    = (bf16*)alloc((size_t)MPAD * (3 * D_ + D_) * 2);
  bf16* qkv    = big;
  bf16* attn   = big + (size_t)MPAD * 3 * D_;
  bf16* ffn1   = big;   // overlays qkv+attn (both dead by then)

  k_prep<<<8704, 256, 0, stream>>>(
      x, tr_w1, hid,
      in_w, out_w, f1_w, f2_w, w_in, w_out, w_f1, w_f2,
      (float*)d_out,
      t_emb, ln1_w, ln1_b, p1, ln2_w, ln2_b, p2);
  k_imptail<<<B_ * S_ / 256, 256, 0, stream>>>(hid, tr_b1, tr_w2, tr_b2, imp);
  k_rank<<<B_ * 32, 256, 0, stream>>>(imp, rank);
  k_compact<<<B_, 256, 0, stream>>>(rank, idx);

  k_adaln<<<MPAD, 256, 0, stream>>>(x, idx, p1, h_bf);
  k_gemm<128, 0><<<46 * 24, 256, 0, stream>>>(
      h_bf, w_in, in_b, qkv, nullptr, nullptr, nullptr, 3 * D_, D_, 24);
  k_attn<<<QT64 * H_ * B_, 256, 0, stream>>>(qkv, attn);
  k_gemm<64, 2><<<46 * 16, 256, 0, stream>>>(
      attn, w_out, out_b, nullptr, gate_a, idx, (float*)d_out, D_, D_, 16);
  k_adaln<<<MPAD, 256, 0, stream>>>((const float*)d_out, idx, p2, h_bf);
  k_gemm<128, 1><<<46 * 32, 256, 0, stream>>>(
      h_bf, w_f1, f1_b, ffn1, nullptr, nullptr, nullptr, DFF_, D_, 32);
  k_gemm<64, 2><<<46 * 16, 256, 0, stream>>>(
      ffn1, w_f2, f2_b, nullptr, gate_f, idx, (float*)d_out, D_, DFF_, 16);
}

// Round 18
// 407.701 us; speedup vs baseline: 1.0928x; 1.0339x over previous
//
#include <hip/hip_runtime.h>
#include <hip/hip_bf16.h>
#include <cmath>
#include <cstdint>

typedef __bf16 bf16;
typedef __bf16 bf16x8 __attribute__((ext_vector_type(8)));
typedef __bf16 bf16x4 __attribute__((ext_vector_type(4)));
typedef float  f32x4  __attribute__((ext_vector_type(4)));

constexpr int B_   = 4;
constexpr int S_   = 2048;
constexpr int D_   = 1024;
constexpr int H_   = 16;
constexpr int DFF_ = 4096;
constexpr int TD_  = 256;
constexpr int KEEP = 1433;              // int(2048*0.7)
constexpr int M_TOT = B_ * KEEP;        // 5732
constexpr int MPAD  = 5888;             // 46*128
constexpr int QT64  = (KEEP + 63) / 64; // 23
constexpr int NKV   = (KEEP + 63) / 64; // 23
constexpr float EPS = 1e-5f;
// 1/sqrt(64) * log2(e): folded into Q in the QKV epilogue; attn uses exp2.
constexpr float QSCALE = 0.18033688011112042f;

__device__ __forceinline__ f32x4 mfma16(bf16x8 a, bf16x8 b, f32x4 c) {
  return __builtin_amdgcn_mfma_f32_16x16x32_bf16(a, b, c, 0, 0, 0);
}

#define GLOAD_LDS(gp, lp)                                                     \
  __builtin_amdgcn_global_load_lds(                                           \
      (const __attribute__((address_space(1))) void*)(gp),                    \
      (__attribute__((address_space(3))) void*)(lp), 16, 0, 0)

// ---------------- fused prep ------------------------------------------------
// [0,2048)     importance GEMV (u0 slow index -> same-XCD x reuse);
//              reduction via LDS transpose
// [2048,3584)  fp32->bf16 weight casts, 8 float4/thread
// [3584,4608)  d_out = x copy, 8 float4/thread
// [4608,8704)  cond projections x2
__global__ __launch_bounds__(256) void k_prep(
    const float* __restrict__ x, const float* __restrict__ tr_w1,
    double* __restrict__ hidden,
    const float* __restrict__ in_w, const float* __restrict__ out_w,
    const float* __restrict__ f1_w, const float* __restrict__ f2_w,
    bf16* __restrict__ w_in, bf16* __restrict__ w_out,
    bf16* __restrict__ w_f1, bf16* __restrict__ w_f2,
    float* __restrict__ dout,
    const float* __restrict__ temb,
    const float* __restrict__ ln1_w, const float* __restrict__ ln1_b,
    float* __restrict__ p1,
    const float* __restrict__ ln2_w, const float* __restrict__ ln2_b,
    float* __restrict__ p2)
{
  __shared__ double sred[4][64][17];   // per-wave [src lane][16 accs + pad]
  const int bid = blockIdx.x;
  if (bid < 2048) {
    // ---- importance GEMV: 4 tokens x 8 units per wave, fp64 accumulate
    const int lane = threadIdx.x & 63, w = threadIdx.x >> 6;
    const int tok0 = (bid & 511) * 16 + w * 4;
    const int u0 = (bid >> 9) * 8;
    const float* xb = x + (size_t)tok0 * D_ + lane * 4;
    const float* wb = tr_w1 + (size_t)u0 * D_ + lane * 4;
    double acc[4][8] = {};
#pragma unroll 2
    for (int c = 0; c < D_; c += 256) {
      float4 xv[4], wv[8];
#pragma unroll
      for (int i = 0; i < 4; ++i)
        xv[i] = *(const float4*)(xb + (size_t)i * D_ + c);
#pragma unroll
      for (int u = 0; u < 8; ++u)
        wv[u] = *(const float4*)(wb + (size_t)u * D_ + c);
#pragma unroll
      for (int i = 0; i < 4; ++i)
#pragma unroll
        for (int u = 0; u < 8; ++u) {
          acc[i][u] += (double)xv[i].x * (double)wv[u].x;
          acc[i][u] += (double)xv[i].y * (double)wv[u].y;
          acc[i][u] += (double)xv[i].z * (double)wv[u].z;
          acc[i][u] += (double)xv[i].w * (double)wv[u].w;
        }
    }
    // ---- LDS-transpose reduction: 2 batches of 16 accs.
    double* my = &sred[w][0][0];
#pragma unroll
    for (int bt = 0; bt < 2; ++bt) {
#pragma unroll
      for (int a = 0; a < 16; ++a)
        my[lane * 17 + a] = acc[2 * bt + (a >> 3)][a & 7];
      asm volatile("s_waitcnt lgkmcnt(0)" ::: "memory");
      __builtin_amdgcn_sched_barrier(0);
      const int a = lane >> 2, sl = lane & 3;
      const double* rp = my + (sl * 16) * 17 + a;
      double s0 = rp[0]        + rp[17];
      double s1 = rp[2  * 17]  + rp[3  * 17];
      double s2 = rp[4  * 17]  + rp[5  * 17];
      double s3 = rp[6  * 17]  + rp[7  * 17];
      s0 += rp[8  * 17]; s1 += rp[9  * 17];
      s2 += rp[10 * 17]; s3 += rp[11 * 17];
      s0 += rp[12 * 17]; s1 += rp[13 * 17];
      s2 += rp[14 * 17]; s3 += rp[15 * 17];
      double s = (s0 + s1) + (s2 + s3);
      s += __shfl_xor(s, 1);
      s += __shfl_xor(s, 2);
      if (sl == 0)
        hidden[(size_t)(tok0 + 2 * bt + (a >> 3)) * 32 + u0 + (a & 7)] = s;
      asm volatile("s_waitcnt lgkmcnt(0)" ::: "memory");
      __builtin_amdgcn_sched_barrier(0);
    }
  } else if (bid < 3584) {
    // ---- fp32 -> bf16 weight casts: 8 float4 per thread
    const int base = (bid - 2048) * 2048 + threadIdx.x;
#pragma unroll
    for (int k2 = 0; k2 < 8; ++k2) {
      const int g = base + k2 * 256;
      const float* src; bf16* dst; int off;
      if (g < 786432)       { src = in_w;  dst = w_in;  off = g; }
      else if (g < 1048576) { src = out_w; dst = w_out; off = g - 786432; }
      else if (g < 2097152) { src = f1_w;  dst = w_f1;  off = g - 1048576; }
      else                  { src = f2_w;  dst = w_f2;  off = g - 2097152; }
      float4 v = ((const float4*)src)[off];
      bf16x4 o = {(bf16)v.x, (bf16)v.y, (bf16)v.z, (bf16)v.w};
      ((bf16x4*)dst)[off] = o;
    }
  } else if (bid < 4608) {
    // ---- d_out = x: 8 float4 per thread
    const int base = (bid - 3584) * 2048 + threadIdx.x;
    float4 v[8];
#pragma unroll
    for (int k2 = 0; k2 < 8; ++k2) v[k2] = ((const float4*)x)[base + k2 * 256];
#pragma unroll
    for (int k2 = 0; k2 < 8; ++k2) ((float4*)dout)[base + k2 * 256] = v[k2];
  } else {
    // ---- cond projections
    int gw = (int)(((bid - 4608) * 256 + threadIdx.x) >> 6);
    const int lane = threadIdx.x & 63;
    const float* W = ln1_w; const float* bias = ln1_b; float* p = p1;
    if (gw >= 8192) { gw -= 8192; W = ln2_w; bias = ln2_b; p = p2; }
    const int b = gw >> 11;
    const int row = gw & 2047;
    const float* te = temb + (size_t)b * TD_;
    const float* wr = W + (size_t)row * TD_;
    float acc = 0.f;
    for (int i = lane; i < TD_; i += 64) {
      float c = te[i];
      acc += (c / (1.f + __expf(-c))) * wr[i];
    }
    for (int o = 32; o > 0; o >>= 1) acc += __shfl_down(acc, o);
    if (lane == 0) p[(size_t)b * 2 * D_ + row] = acc + bias[row];
  }
}

// ---------------- importance tail: imp = silu(hidden + b1) . w2 + b2 --------
__global__ __launch_bounds__(256) void k_imptail(
    const double* __restrict__ hidden, const float* __restrict__ b1,
    const float* __restrict__ w2, const float* __restrict__ b2,
    double* __restrict__ imp)
{
  const int tok = blockIdx.x * 256 + threadIdx.x;
  const double* hp = hidden + (size_t)tok * 32;
  double r = 0.0;
#pragma unroll
  for (int u = 0; u < 32; ++u) {
    double s = hp[u] + (double)b1[u];
    double sv = s / (1.0 + exp(-s));
    r += sv * (double)w2[u];
  }
  imp[tok] = r + (double)b2[0];
}

// ---------------- rank: #(greater) or (equal && earlier) ---------------------
__global__ __launch_bounds__(256) void k_rank(const double* __restrict__ imp,
                                              int* __restrict__ rank)
{
  const int b = blockIdx.x >> 5;
  const int seg = blockIdx.x & 31;     // 64 tokens per block
  __shared__ double vals[S_];
  const double* ib = imp + (size_t)b * S_;
  for (int i = threadIdx.x; i < S_ / 2; i += 256)
    ((double2*)vals)[i] = ((const double2*)ib)[i];
  __syncthreads();
  const int tl = threadIdx.x >> 2;     // token within segment
  const int part = threadIdx.x & 3;    // quarter of the scan
  const int s = seg * 64 + tl;
  const double v = vals[s];
  int cnt = 0;
  for (int j = part * 512; j < (part + 1) * 512; ++j) {
    double u = vals[j];
    cnt += (u > v) || (u == v && j < s);
  }
  cnt += __shfl_xor(cnt, 1);
  cnt += __shfl_xor(cnt, 2);
  if (part == 0) rank[b * S_ + s] = cnt;
}

// ---------------- compact kept indices (ascending) ---------------------------
__global__ __launch_bounds__(256) void k_compact(const int* __restrict__ rank,
                                                 int* __restrict__ idx)
{
  const int b = blockIdx.x;
  __shared__ int wcnt[4];
  __shared__ int base_s;
  if (threadIdx.x == 0) base_s = 0;
  __syncthreads();
  const int t = threadIdx.x, lane = t & 63, w = t >> 6;
  for (int c = 0; c < S_ / 256; ++c) {
    const int s = c * 256 + t;
    const bool kept = rank[b * S_ + s] < KEEP;
    unsigned long long m = __ballot(kept);
    int piw = __popcll(m & ((1ull << lane) - 1ull));
    if (lane == 0) wcnt[w] = __popcll(m);
    __syncthreads();
    int off = base_s;
    for (int i = 0; i < w; ++i) off += wcnt[i];
    if (kept) idx[b * KEEP + off + piw] = s;
    __syncthreads();
    if (t == 0) base_s += wcnt[0] + wcnt[1] + wcnt[2] + wcnt[3];
    __syncthreads();
  }
}

// ---------------- gather + adaLN -> bf16 -------------------------------------
__global__ __launch_bounds__(256) void k_adaln(
    const float* __restrict__ xsrc, const int* __restrict__ idx,
    const float* __restrict__ p, bf16* __restrict__ hout)
{
  const int r = blockIdx.x, t = threadIdx.x;
  bf16* orow = hout + (size_t)r * D_;
  if (r >= M_TOT) {
    bf16x4 z = {(bf16)0.f, (bf16)0.f, (bf16)0.f, (bf16)0.f};
    ((bf16x4*)orow)[t] = z;
    return;
  }
  const int b = r / KEEP, j = r - b * KEEP;
  const int s = idx[b * KEEP + j];
  const float* xr = xsrc + ((size_t)(b * S_ + s)) * D_;
  float4 v = ((const float4*)xr)[t];
  __shared__ float red[8];
  float sum = v.x + v.y + v.z + v.w;
  for (int o = 32; o > 0; o >>= 1) sum += __shfl_down(sum, o);
  const int lane = t & 63, w = t >> 6;
  if (lane == 0) red[w] = sum;
  __syncthreads();
  const float mu = (red[0] + red[1] + red[2] + red[3]) * (1.f / D_);
  const float dx = v.x - mu, dy = v.y - mu, dz = v.z - mu, dw = v.w - mu;
  float vs = dx * dx + dy * dy + dz * dz + dw * dw;
  for (int o = 32; o > 0; o >>= 1) vs += __shfl_down(vs, o);
  if (lane == 0) red[4 + w] = vs;
  __syncthreads();
  const float rstd = rsqrtf((red[4] + red[5] + red[6] + red[7]) * (1.f / D_) + EPS);
  const float* gp = p + (size_t)b * 2 * D_;
  float4 g  = ((const float4*)gp)[t];
  float4 be = ((const float4*)(gp + D_))[t];
  bf16x4 o;
  o[0] = (bf16)(dx * rstd * (1.f + g.x) + be.x);
  o[1] = (bf16)(dy * rstd * (1.f + g.y) + be.y);
  o[2] = (bf16)(dz * rstd * (1.f + g.z) + be.z);
  o[3] = (bf16)(dw * rstd * (1.f + g.w) + be.w);
  ((bf16x4*)orow)[t] = o;
}

// ---------------- GEMM 128xBN, BK=64 (3-bit swizzle: 0 bank conflicts) ------
// 2-phase dbuf, hoisted staging pointers, bijective XCD remap.
// MODE 0: bias (+QSCALE on Q third) -> bf16. MODE 1: bias+gelu -> bf16.
// MODE 2: bias, then resid[row(m)][n] += gate[n]*v (gathered residual).
template <int BN, int MODE>
__global__ __launch_bounds__(256) void k_gemm(
    const bf16* __restrict__ A, const bf16* __restrict__ W,
    const float* __restrict__ bias, bf16* __restrict__ Cbf,
    const float* __restrict__ gate, const int* __restrict__ idx,
    float* __restrict__ resid, int N, int K, int gn)
{
  constexpr int WN = BN / 2;      // per-wave N span
  constexpr int NJ = WN / 16;     // N fragments per wave
  constexpr int WIT = BN / 32;    // W staging iterations
  __shared__ bf16 As[2][128 * 64];
  __shared__ bf16 Ws[2][BN * 64];
  const int t = threadIdx.x, lane = t & 63;
  const int w = t >> 6, wr = w >> 1, wc = w & 1;
  const int fr = lane & 15, fq = lane >> 4;

  // bijective XCD-contiguous remap (m204)
  const int nwg = gridDim.x, orig = blockIdx.x;
  const int q8 = nwg >> 3, r8 = nwg & 7;
  const int xc = orig & 7, pos = orig >> 3;
  const int wgid = (xc < r8 ? xc * (q8 + 1) : r8 * (q8 + 1) + (xc - r8) * q8) + pos;
  const int bm = wgid / gn, bn = wgid - bm * gn;

  const bf16* Ab = A + (size_t)bm * 128 * K;
  const bf16* Wb = W + (size_t)bn * BN * K;

  // tile-invariant per-thread staging pointers (advance += 64 per tile)
  const bf16* pA[4];
  const bf16* pW[WIT];
#pragma unroll
  for (int it = 0; it < 4; ++it) {
    const int e = it * 256 + t;
    const int row = e >> 3, pc = e & 7;
    const int lc = pc ^ (row & 7);
    pA[it] = Ab + (size_t)row * K + lc * 8;
  }
#pragma unroll
  for (int it = 0; it < WIT; ++it) {
    const int e = it * 256 + t;
    const int row = e >> 3, pc = e & 7;
    const int lc = pc ^ (row & 7);
    pW[it] = Wb + (size_t)row * K + lc * 8;
  }

  auto stage = [&](int buf) {
#pragma unroll
    for (int it = 0; it < 4; ++it) {
      GLOAD_LDS(pA[it], &As[buf][0] + (it * 256 + t) * 8);
      pA[it] += 64;
    }
#pragma unroll
    for (int it = 0; it < WIT; ++it) {
      GLOAD_LDS(pW[it], &Ws[buf][0] + (it * 256 + t) * 8);
      pW[it] += 64;
    }
  };

  f32x4 acc[4][NJ] = {};
  stage(0);
  const int nkt = K >> 6;
  int cur = 0;
  for (int kt = 0; kt < nkt; ++kt) {
    __syncthreads();                   // stage(cur) landed; prev reads done
    if (kt + 1 < nkt) stage(cur ^ 1);
    const char* Al = (const char*)&As[cur][0];
    const char* Wl = (const char*)&Ws[cur][0];
#pragma unroll
    for (int kk = 0; kk < 2; ++kk) {
      bf16x8 af[4], wf[NJ];
#pragma unroll
      for (int i = 0; i < 4; ++i)
        af[i] = *(const bf16x8*)(Al + (wr * 64 + i * 16 + fr) * 128 +
                                 (((kk * 4 + fq) ^ (fr & 7)) << 4));
#pragma unroll
      for (int j = 0; j < NJ; ++j)
        wf[j] = *(const bf16x8*)(Wl + (wc * WN + j * 16 + fr) * 128 +
                                 (((kk * 4 + fq) ^ (fr & 7)) << 4));
#pragma unroll
      for (int i = 0; i < 4; ++i)
#pragma unroll
        for (int j = 0; j < NJ; ++j)
          acc[i][j] = mfma16(af[i], wf[j], acc[i][j]);
    }
    cur ^= 1;
  }

  if (MODE == 2) {
    // per output row compute idx/gather once, then sweep n
#pragma unroll
    for (int i = 0; i < 4; ++i) {
#pragma unroll
      for (int r = 0; r < 4; ++r) {
        const int m = bm * 128 + wr * 64 + i * 16 + fq * 4 + r;
        if (m < M_TOT) {
          const int b = m / KEEP, jj = m - b * KEEP;
          const int s = idx[b * KEEP + jj];
          float* rp = resid + ((size_t)(b * S_ + s)) * D_ + bn * BN + wc * WN + fr;
          const float* gp = gate + bn * BN + wc * WN + fr;
          const float* bp = bias + bn * BN + wc * WN + fr;
#pragma unroll
          for (int j = 0; j < NJ; ++j)
            rp[j * 16] += gp[j * 16] * (acc[i][j][r] + bp[j * 16]);
        }
      }
    }
  } else {
#pragma unroll
    for (int i = 0; i < 4; ++i) {
#pragma unroll
      for (int j = 0; j < NJ; ++j) {
#pragma unroll
        for (int r = 0; r < 4; ++r) {
          const int m = bm * 128 + wr * 64 + i * 16 + fq * 4 + r;
          const int n = bn * BN + wc * WN + j * 16 + fr;
          float v = acc[i][j][r] + bias[n];
          if (MODE == 0) {
            if (n < D_) v *= QSCALE;
            Cbf[(size_t)m * N + n] = (bf16)v;
          } else {
            float gl = 0.5f * v * (1.f + erff(v * 0.70710678118654752f));
            Cbf[(size_t)m * N + n] = (bf16)gl;
          }
        }
      }
    }
  }
}

// ---------------- flash attention: swapped-QK^T, in-register softmax ---------
// XCD-contiguous 1D grid + hoisted V tr-reads (round-11 config).
__global__ __launch_bounds__(256) void k_attn(const bf16* __restrict__ qkv,
                                              bf16* __restrict__ out)
{
  __shared__ bf16 Klds[2][64 * 64];
  __shared__ bf16 Vlds[2][64 * 64];

  const int t = threadIdx.x;
  const int lane = t & 63, w = t >> 6;
  const int fr = lane & 15, fq = lane >> 4;

  const int orig = blockIdx.x;
  const int wgid = (orig & 7) * 184 + (orig >> 3);
  const int qt = wgid % QT64;
  const int hb = wgid / QT64;
  const int h = hb & 15, b = hb >> 4;

  const size_t rowbase = (size_t)b * KEEP;
  const size_t RS = 3 * D_;
  const bf16* kbase = qkv + rowbase * RS + D_ + h * 64;
  const bf16* vbase = qkv + rowbase * RS + 2 * D_ + h * 64;

  const int wq0 = qt * 64 + w * 16;
  const int qrow = min(wq0 + fr, KEEP - 1);
  const bf16* qp = qkv + (rowbase + qrow) * RS + h * 64 + fq * 8;
  const bf16x8 qf0 = *(const bf16x8*)qp;          // Q as B-operand, d<32
  const bf16x8 qf1 = *(const bf16x8*)(qp + 32);   // d>=32

  f32x4 o[4] = {};
  float mrow = -INFINITY, lrow = 0.f;

  const int p0 = t, p1 = 256 + t;
  auto kaddr = [&](int p, int kv) {
    const int row = p >> 3, c8p = p & 7;
    const int c8 = c8p ^ ((row & 7) ^ (row >> 3));
    const int gr = min(kv + row, KEEP - 1);
    return kbase + (size_t)gr * RS + c8 * 8;
  };
  auto vaddr = [&](int p, int kv) {
    const int db = p >> 7, ksub = (p >> 3) & 15, jr = (p >> 1) & 3,
              c8lo = p & 1;
    const int vrow = ksub * 4 + jr, vc8 = db * 2 + c8lo;
    const int gr = min(kv + vrow, KEEP - 1);
    return vbase + (size_t)gr * RS + vc8 * 8;
  };
  const bf16* kp0 = kaddr(p0, 0);
  const bf16* kp1 = kaddr(p1, 0);
  const bf16* vp0 = vaddr(p0, 0);
  const bf16* vp1 = vaddr(p1, 0);

  auto stage_fast = [&](int buf) {
    GLOAD_LDS(kp0, &Klds[buf][0] + p0 * 8);
    GLOAD_LDS(kp1, &Klds[buf][0] + p1 * 8);
    GLOAD_LDS(vp0, &Vlds[buf][0] + p0 * 8);
    GLOAD_LDS(vp1, &Vlds[buf][0] + p1 * 8);
    kp0 += 64 * RS; kp1 += 64 * RS; vp0 += 64 * RS; vp1 += 64 * RS;
  };
  auto stage_last = [&](int buf, int kv) {
    GLOAD_LDS(kaddr(p0, kv), &Klds[buf][0] + p0 * 8);
    GLOAD_LDS(kaddr(p1, kv), &Klds[buf][0] + p1 * 8);
    GLOAD_LDS(vaddr(p0, kv), &Vlds[buf][0] + p0 * 8);
    GLOAD_LDS(vaddr(p1, kv), &Vlds[buf][0] + p1 * 8);
  };

  stage_fast(0);
  int cur = 0;

  const unsigned vbase_lds0 =
      (unsigned)(size_t)(__attribute__((address_space(3))) bf16*)&Vlds[0][0];
  const unsigned vbase_lds1 =
      (unsigned)(size_t)(__attribute__((address_space(3))) bf16*)&Vlds[1][0];

  for (int ti = 0; ti < NKV; ++ti) {
    const int kv = ti * 64;
    __syncthreads();
    if (ti < NKV - 2) stage_fast(cur ^ 1);
    else if (ti == NKV - 2) stage_last(cur ^ 1, kv + 64);

    const char* Kl = (const char*)&Klds[cur][0];

    f32x4 sc[4];
    __builtin_amdgcn_s_setprio(1);
#pragma unroll
    for (int f = 0; f < 4; ++f) {
      const int row = ((f >> 1) << 5) + ((fr >> 2) << 3) + ((f & 1) << 1) +
                      (fr & 1) + (((fr >> 1) & 1) << 2);
      const int swz = (row & 7) ^ (row >> 3);
      const bf16x8 kf0 = *(const bf16x8*)(Kl + row * 128 + ((fq ^ swz) << 4));
      const bf16x8 kf1 =
          *(const bf16x8*)(Kl + row * 128 + (((fq ^ 4) ^ swz) << 4));
      f32x4 s = {0.f, 0.f, 0.f, 0.f};
      s = mfma16(kf0, qf0, s);
      s = mfma16(kf1, qf1, s);
      sc[f] = s;
    }
    __builtin_amdgcn_s_setprio(0);

    // issue ALL V tr-reads now (no wait): overlap the softmax VALU
    const unsigned vb =
        (cur ? vbase_lds1 : vbase_lds0) + ((unsigned)fq << 7);
    bf16x4 v0[8], v1[8];
    asm volatile(
        "ds_read_b64_tr_b16 %0, %8 offset:0\n\t"
        "ds_read_b64_tr_b16 %1, %8 offset:128\n\t"
        "ds_read_b64_tr_b16 %2, %8 offset:2048\n\t"
        "ds_read_b64_tr_b16 %3, %8 offset:2176\n\t"
        "ds_read_b64_tr_b16 %4, %8 offset:4096\n\t"
        "ds_read_b64_tr_b16 %5, %8 offset:4224\n\t"
        "ds_read_b64_tr_b16 %6, %8 offset:6144\n\t"
        "ds_read_b64_tr_b16 %7, %8 offset:6272"
        : "=&v"(v0[0]), "=&v"(v0[1]), "=&v"(v0[2]), "=&v"(v0[3]),
          "=&v"(v0[4]), "=&v"(v0[5]), "=&v"(v0[6]), "=&v"(v0[7])
        : "v"(vb));
    asm volatile(
        "ds_read_b64_tr_b16 %0, %8 offset:1024\n\t"
        "ds_read_b64_tr_b16 %1, %8 offset:1152\n\t"
        "ds_read_b64_tr_b16 %2, %8 offset:3072\n\t"
        "ds_read_b64_tr_b16 %3, %8 offset:3200\n\t"
        "ds_read_b64_tr_b16 %4, %8 offset:5120\n\t"
        "ds_read_b64_tr_b16 %5, %8 offset:5248\n\t"
        "ds_read_b64_tr_b16 %6, %8 offset:7168\n\t"
        "ds_read_b64_tr_b16 %7, %8 offset:7296"
        : "=&v"(v1[0]), "=&v"(v1[1]), "=&v"(v1[2]), "=&v"(v1[3]),
          "=&v"(v1[4]), "=&v"(v1[5]), "=&v"(v1[6]), "=&v"(v1[7])
        : "v"(vb));

    if (ti == NKV - 1) {
#pragma unroll
      for (int f = 0; f < 4; ++f)
#pragma unroll
        for (int r = 0; r < 4; ++r) {
          const int kl = ((f >> 1) << 5) + (fq << 3) + ((f & 1) << 1) +
                         (r & 1) + ((r >> 1) << 2);
          if (kv + kl >= KEEP) sc[f][r] = -INFINITY;
        }
    }
    float m0 = fmaxf(fmaxf(sc[0][0], sc[0][1]), sc[0][2]);
    float m1 = fmaxf(fmaxf(sc[0][3], sc[1][0]), sc[1][1]);
    float m2 = fmaxf(fmaxf(sc[1][2], sc[1][3]), sc[2][0]);
    float m3 = fmaxf(fmaxf(sc[2][1], sc[2][2]), sc[2][3]);
    float m4 = fmaxf(fmaxf(sc[3][0], sc[3][1]), sc[3][2]);
    float mx = fmaxf(fmaxf(m0, m1), m2);
    mx = fmaxf(fmaxf(mx, m3), fmaxf(m4, sc[3][3]));
    mx = fmaxf(mx, __shfl_xor(mx, 16));
    mx = fmaxf(mx, __shfl_xor(mx, 32));

    const bool noresc = __all(mx <= mrow + 8.f);
    const float mnew = noresc ? mrow : fmaxf(mrow, mx);
    float ps = 0.f;
    bf16 pe[4][4];
#pragma unroll
    for (int f = 0; f < 4; ++f)
#pragma unroll
      for (int r = 0; r < 4; ++r) {
        const float pv = exp2f(sc[f][r] - mnew);
        ps += pv;
        pe[f][r] = (bf16)pv;
      }
    ps += __shfl_xor(ps, 16);
    ps += __shfl_xor(ps, 32);
    if (!noresc) {
      const float fac = exp2f(mrow - mnew);
      lrow *= fac;
#pragma unroll
      for (int db = 0; db < 4; ++db) {
        o[db][0] *= fac; o[db][1] *= fac; o[db][2] *= fac; o[db][3] *= fac;
      }
      mrow = mnew;
    }
    lrow += ps;

    const bf16x8 pb[2] = {
        {pe[0][0], pe[0][1], pe[1][0], pe[1][1],
         pe[0][2], pe[0][3], pe[1][2], pe[1][3]},
        {pe[2][0], pe[2][1], pe[3][0], pe[3][1],
         pe[2][2], pe[2][3], pe[3][2], pe[3][3]}};

    asm volatile("s_waitcnt lgkmcnt(0)" ::: "memory");
    __builtin_amdgcn_sched_barrier(0);

    const bf16x8 vf00 = __builtin_shufflevector(v0[0], v0[1], 0,1,2,3,4,5,6,7);
    const bf16x8 vf01 = __builtin_shufflevector(v0[2], v0[3], 0,1,2,3,4,5,6,7);
    const bf16x8 vf02 = __builtin_shufflevector(v0[4], v0[5], 0,1,2,3,4,5,6,7);
    const bf16x8 vf03 = __builtin_shufflevector(v0[6], v0[7], 0,1,2,3,4,5,6,7);
    const bf16x8 vf10 = __builtin_shufflevector(v1[0], v1[1], 0,1,2,3,4,5,6,7);
    const bf16x8 vf11 = __builtin_shufflevector(v1[2], v1[3], 0,1,2,3,4,5,6,7);
    const bf16x8 vf12 = __builtin_shufflevector(v1[4], v1[5], 0,1,2,3,4,5,6,7);
    const bf16x8 vf13 = __builtin_shufflevector(v1[6], v1[7], 0,1,2,3,4,5,6,7);
    __builtin_amdgcn_s_setprio(1);
    o[0] = mfma16(vf00, pb[0], o[0]);
    o[1] = mfma16(vf01, pb[0], o[1]);
    o[2] = mfma16(vf02, pb[0], o[2]);
    o[3] = mfma16(vf03, pb[0], o[3]);
    o[0] = mfma16(vf10, pb[1], o[0]);
    o[1] = mfma16(vf11, pb[1], o[1]);
    o[2] = mfma16(vf12, pb[1], o[2]);
    o[3] = mfma16(vf13, pb[1], o[3]);
    __builtin_amdgcn_s_setprio(0);
    cur ^= 1;
  }

  const int q = wq0 + fr;
  if (q < KEEP) {
    const float inv = 1.f / lrow;
#pragma unroll
    for (int db = 0; db < 4; ++db) {
      bf16x4 wv = {(bf16)(o[db][0] * inv), (bf16)(o[db][1] * inv),
                   (bf16)(o[db][2] * inv), (bf16)(o[db][3] * inv)};
      *(bf16x4*)(out + (rowbase + q) * (size_t)D_ + h * 64 + db * 16 + fq * 4) =
          wv;
    }
  }
}

// ----------------------------------------------------------------------------
extern "C" void kernel_launch(void* const* d_in, const int* in_sizes, int n_in,
                              void* d_out, int out_size, void* d_ws, size_t ws_size,
                              hipStream_t stream)
{
  (void)in_sizes; (void)n_in; (void)out_size; (void)ws_size;
  const float* x      = (const float*)d_in[0];
  const float* t_emb  = (const float*)d_in[1];
  const float* tr_w1  = (const float*)d_in[2];
  const float* tr_b1  = (const float*)d_in[3];
  const float* tr_w2  = (const float*)d_in[4];
  const float* tr_b2  = (const float*)d_in[5];
  const float* ln1_w  = (const float*)d_in[6];
  const float* ln1_b  = (const float*)d_in[7];
  const float* ln2_w  = (const float*)d_in[8];
  const float* ln2_b  = (const float*)d_in[9];
  const float* in_w   = (const float*)d_in[10];
  const float* in_b   = (const float*)d_in[11];
  const float* out_w  = (const float*)d_in[12];
  const float* out_b  = (const float*)d_in[13];
  const float* f1_w   = (const float*)d_in[14];
  const float* f1_b   = (const float*)d_in[15];
  const float* f2_w   = (const float*)d_in[16];
  const float* f2_b   = (const float*)d_in[17];
  const float* gate_a = (const float*)d_in[18];
  const float* gate_f = (const float*)d_in[19];

  char* ws = (char*)d_ws;
  size_t off = 0;
  auto alloc = [&](size_t bytes) -> char* {
    char* p = ws + off;
    off = (off + bytes + 255) & ~(size_t)255;
    return p;
  };
  double* imp  = (double*)alloc((size_t)B_ * S_ * 8);
  double* hid  = (double*)alloc((size_t)B_ * S_ * 32 * 8);
  int* rank    = (int*)alloc((size_t)B_ * S_ * 4);
  int* idx     = (int*)alloc((size_t)B_ * KEEP * 4);
  float* p1    = (float*)alloc((size_t)B_ * 2 * D_ * 4);
  float* p2    = (float*)alloc((size_t)B_ * 2 * D_ * 4);
  bf16* w_in   = (bf16*)alloc((size_t)3 * D_ * D_ * 2);
  bf16* w_out  = (bf16*)alloc((size_t)D_ * D_ * 2);
  bf16* w_f1   = (bf16*)alloc((size_t)DFF_ * D_ * 2);
  bf16* w_f2   = (bf16*)alloc((size_t)D_ * DFF_ * 2);
  bf16* h_bf   = (bf16*)alloc((size_t)MPAD * D_ * 2);
  bf16* big    = (bf16*)alloc((size_t)MPAD * (3 * D_ + D_) * 2);
  bf16* qkv    = big;
  bf16* attn   = big + (size_t)MPAD * 3 * D_;
  bf16* ffn1   = big;   // overlays qkv+attn (both dead by then)

  k_prep<<<8704, 256, 0, stream>>>(
      x, tr_w1, hid,
      in_w, out_w, f1_w, f2_w, w_in, w_out, w_f1, w_f2,
      (float*)d_out,
      t_emb, ln1_w, ln1_b, p1, ln2_w, ln2_b, p2);
  k_imptail<<<B_ * S_ / 256, 256, 0, stream>>>(hid, tr_b1, tr_w2, tr_b2, imp);
  k_rank<<<B_ * 32, 256, 0, stream>>>(imp, rank);
  k_compact<<<B_, 256, 0, stream>>>(rank, idx);

  k_adaln<<<MPAD, 256, 0, stream>>>(x, idx, p1, h_bf);
  k_gemm<128, 0><<<46 * 24, 256, 0, stream>>>(
      h_bf, w_in, in_b, qkv, nullptr, nullptr, nullptr, 3 * D_, D_, 24);
  k_attn<<<QT64 * H_ * B_, 256, 0, stream>>>(qkv, attn);
  k_gemm<64, 2><<<46 * 16, 256, 0, stream>>>(
      attn, w_out, out_b, nullptr, gate_a, idx, (float*)d_out, D_, D_, 16);
  k_adaln<<<MPAD, 256, 0, stream>>>((const float*)d_out, idx, p2, h_bf);
  k_gemm<128, 1><<<46 * 32, 256, 0, stream>>>(
      h_bf, w_f1, f1_b, ffn1, nullptr, nullptr, nullptr, DFF_, D_, 32);
  k_gemm<64, 2><<<46 * 16, 256, 0, stream>>>(
      ffn1, w_f2, f2_b, nullptr, gate_f, idx, (float*)d_out, D_, DFF_, 16);
}

// Round 19
// 402.485 us; speedup vs baseline: 1.1069x; 1.0130x over previous
//
#include <hip/hip_runtime.h>
#include <hip/hip_bf16.h>
#include <cmath>
#include <cstdint>

typedef __bf16 bf16;
typedef __bf16 bf16x8 __attribute__((ext_vector_type(8)));
typedef __bf16 bf16x4 __attribute__((ext_vector_type(4)));
typedef float  f32x4  __attribute__((ext_vector_type(4)));

constexpr int B_   = 4;
constexpr int S_   = 2048;
constexpr int D_   = 1024;
constexpr int H_   = 16;
constexpr int DFF_ = 4096;
constexpr int TD_  = 256;
constexpr int KEEP = 1433;              // int(2048*0.7)
constexpr int M_TOT = B_ * KEEP;        // 5732
constexpr int MPAD  = 5888;             // 46*128
constexpr int QT128 = (KEEP + 127) / 128; // 12
constexpr int NKV   = (KEEP + 63) / 64;   // 23
constexpr float EPS = 1e-5f;
// 1/sqrt(64) * log2(e): folded into Q in the QKV epilogue; attn uses exp2.
constexpr float QSCALE = 0.18033688011112042f;

__device__ __forceinline__ f32x4 mfma16(bf16x8 a, bf16x8 b, f32x4 c) {
  return __builtin_amdgcn_mfma_f32_16x16x32_bf16(a, b, c, 0, 0, 0);
}

#define GLOAD_LDS(gp, lp)                                                     \
  __builtin_amdgcn_global_load_lds(                                           \
      (const __attribute__((address_space(1))) void*)(gp),                    \
      (__attribute__((address_space(3))) void*)(lp), 16, 0, 0)

// ---------------- fused prep ------------------------------------------------
// [0,2048)     importance GEMV (u0 slow index -> same-XCD x reuse);
//              reduction via LDS transpose
// [2048,3584)  fp32->bf16 weight casts, 8 float4/thread
// [3584,4608)  d_out = x copy, 8 float4/thread
// [4608,8704)  cond projections x2
__global__ __launch_bounds__(256) void k_prep(
    const float* __restrict__ x, const float* __restrict__ tr_w1,
    double* __restrict__ hidden,
    const float* __restrict__ in_w, const float* __restrict__ out_w,
    const float* __restrict__ f1_w, const float* __restrict__ f2_w,
    bf16* __restrict__ w_in, bf16* __restrict__ w_out,
    bf16* __restrict__ w_f1, bf16* __restrict__ w_f2,
    float* __restrict__ dout,
    const float* __restrict__ temb,
    const float* __restrict__ ln1_w, const float* __restrict__ ln1_b,
    float* __restrict__ p1,
    const float* __restrict__ ln2_w, const float* __restrict__ ln2_b,
    float* __restrict__ p2)
{
  __shared__ double sred[4][64][17];   // per-wave [src lane][16 accs + pad]
  const int bid = blockIdx.x;
  if (bid < 2048) {
    // ---- importance GEMV: 4 tokens x 8 units per wave, fp64 accumulate
    const int lane = threadIdx.x & 63, w = threadIdx.x >> 6;
    const int tok0 = (bid & 511) * 16 + w * 4;
    const int u0 = (bid >> 9) * 8;
    const float* xb = x + (size_t)tok0 * D_ + lane * 4;
    const float* wb = tr_w1 + (size_t)u0 * D_ + lane * 4;
    double acc[4][8] = {};
#pragma unroll 2
    for (int c = 0; c < D_; c += 256) {
      float4 xv[4], wv[8];
#pragma unroll
      for (int i = 0; i < 4; ++i)
        xv[i] = *(const float4*)(xb + (size_t)i * D_ + c);
#pragma unroll
      for (int u = 0; u < 8; ++u)
        wv[u] = *(const float4*)(wb + (size_t)u * D_ + c);
#pragma unroll
      for (int i = 0; i < 4; ++i)
#pragma unroll
        for (int u = 0; u < 8; ++u) {
          acc[i][u] += (double)xv[i].x * (double)wv[u].x;
          acc[i][u] += (double)xv[i].y * (double)wv[u].y;
          acc[i][u] += (double)xv[i].z * (double)wv[u].z;
          acc[i][u] += (double)xv[i].w * (double)wv[u].w;
        }
    }
    // ---- LDS-transpose reduction: 2 batches of 16 accs.
    double* my = &sred[w][0][0];
#pragma unroll
    for (int bt = 0; bt < 2; ++bt) {
#pragma unroll
      for (int a = 0; a < 16; ++a)
        my[lane * 17 + a] = acc[2 * bt + (a >> 3)][a & 7];
      asm volatile("s_waitcnt lgkmcnt(0)" ::: "memory");
      __builtin_amdgcn_sched_barrier(0);
      const int a = lane >> 2, sl = lane & 3;
      const double* rp = my + (sl * 16) * 17 + a;
      double s0 = rp[0]        + rp[17];
      double s1 = rp[2  * 17]  + rp[3  * 17];
      double s2 = rp[4  * 17]  + rp[5  * 17];
      double s3 = rp[6  * 17]  + rp[7  * 17];
      s0 += rp[8  * 17]; s1 += rp[9  * 17];
      s2 += rp[10 * 17]; s3 += rp[11 * 17];
      s0 += rp[12 * 17]; s1 += rp[13 * 17];
      s2 += rp[14 * 17]; s3 += rp[15 * 17];
      double s = (s0 + s1) + (s2 + s3);
      s += __shfl_xor(s, 1);
      s += __shfl_xor(s, 2);
      if (sl == 0)
        hidden[(size_t)(tok0 + 2 * bt + (a >> 3)) * 32 + u0 + (a & 7)] = s;
      asm volatile("s_waitcnt lgkmcnt(0)" ::: "memory");
      __builtin_amdgcn_sched_barrier(0);
    }
  } else if (bid < 3584) {
    // ---- fp32 -> bf16 weight casts: 8 float4 per thread
    const int base = (bid - 2048) * 2048 + threadIdx.x;
#pragma unroll
    for (int k2 = 0; k2 < 8; ++k2) {
      const int g = base + k2 * 256;
      const float* src; bf16* dst; int off;
      if (g < 786432)       { src = in_w;  dst = w_in;  off = g; }
      else if (g < 1048576) { src = out_w; dst = w_out; off = g - 786432; }
      else if (g < 2097152) { src = f1_w;  dst = w_f1;  off = g - 1048576; }
      else                  { src = f2_w;  dst = w_f2;  off = g - 2097152; }
      float4 v = ((const float4*)src)[off];
      bf16x4 o = {(bf16)v.x, (bf16)v.y, (bf16)v.z, (bf16)v.w};
      ((bf16x4*)dst)[off] = o;
    }
  } else if (bid < 4608) {
    // ---- d_out = x: 8 float4 per thread
    const int base = (bid - 3584) * 2048 + threadIdx.x;
    float4 v[8];
#pragma unroll
    for (int k2 = 0; k2 < 8; ++k2) v[k2] = ((const float4*)x)[base + k2 * 256];
#pragma unroll
    for (int k2 = 0; k2 < 8; ++k2) ((float4*)dout)[base + k2 * 256] = v[k2];
  } else {
    // ---- cond projections
    int gw = (int)(((bid - 4608) * 256 + threadIdx.x) >> 6);
    const int lane = threadIdx.x & 63;
    const float* W = ln1_w; const float* bias = ln1_b; float* p = p1;
    if (gw >= 8192) { gw -= 8192; W = ln2_w; bias = ln2_b; p = p2; }
    const int b = gw >> 11;
    const int row = gw & 2047;
    const float* te = temb + (size_t)b * TD_;
    const float* wr = W + (size_t)row * TD_;
    float acc = 0.f;
    for (int i = lane; i < TD_; i += 64) {
      float c = te[i];
      acc += (c / (1.f + __expf(-c))) * wr[i];
    }
    for (int o = 32; o > 0; o >>= 1) acc += __shfl_down(acc, o);
    if (lane == 0) p[(size_t)b * 2 * D_ + row] = acc + bias[row];
  }
}

// ---------------- importance tail: imp = silu(hidden + b1) . w2 + b2 --------
__global__ __launch_bounds__(256) void k_imptail(
    const double* __restrict__ hidden, const float* __restrict__ b1,
    const float* __restrict__ w2, const float* __restrict__ b2,
    double* __restrict__ imp)
{
  const int tok = blockIdx.x * 256 + threadIdx.x;
  const double* hp = hidden + (size_t)tok * 32;
  double r = 0.0;
#pragma unroll
  for (int u = 0; u < 32; ++u) {
    double s = hp[u] + (double)b1[u];
    double sv = s / (1.0 + exp(-s));
    r += sv * (double)w2[u];
  }
  imp[tok] = r + (double)b2[0];
}

// ---------------- rank: #(greater) or (equal && earlier) ---------------------
__global__ __launch_bounds__(256) void k_rank(const double* __restrict__ imp,
                                              int* __restrict__ rank)
{
  const int b = blockIdx.x >> 5;
  const int seg = blockIdx.x & 31;     // 64 tokens per block
  __shared__ double vals[S_];
  const double* ib = imp + (size_t)b * S_;
  for (int i = threadIdx.x; i < S_ / 2; i += 256)
    ((double2*)vals)[i] = ((const double2*)ib)[i];
  __syncthreads();
  const int tl = threadIdx.x >> 2;     // token within segment
  const int part = threadIdx.x & 3;    // quarter of the scan
  const int s = seg * 64 + tl;
  const double v = vals[s];
  int cnt = 0;
  for (int j = part * 512; j < (part + 1) * 512; ++j) {
    double u = vals[j];
    cnt += (u > v) || (u == v && j < s);
  }
  cnt += __shfl_xor(cnt, 1);
  cnt += __shfl_xor(cnt, 2);
  if (part == 0) rank[b * S_ + s] = cnt;
}

// ---------------- compact kept indices (ascending) ---------------------------
__global__ __launch_bounds__(256) void k_compact(const int* __restrict__ rank,
                                                 int* __restrict__ idx)
{
  const int b = blockIdx.x;
  __shared__ int wcnt[4];
  __shared__ int base_s;
  if (threadIdx.x == 0) base_s = 0;
  __syncthreads();
  const int t = threadIdx.x, lane = t & 63, w = t >> 6;
  for (int c = 0; c < S_ / 256; ++c) {
    const int s = c * 256 + t;
    const bool kept = rank[b * S_ + s] < KEEP;
    unsigned long long m = __ballot(kept);
    int piw = __popcll(m & ((1ull << lane) - 1ull));
    if (lane == 0) wcnt[w] = __popcll(m);
    __syncthreads();
    int off = base_s;
    for (int i = 0; i < w; ++i) off += wcnt[i];
    if (kept) idx[b * KEEP + off + piw] = s;
    __syncthreads();
    if (t == 0) base_s += wcnt[0] + wcnt[1] + wcnt[2] + wcnt[3];
    __syncthreads();
  }
}

// ---------------- gather + adaLN -> bf16 -------------------------------------
__global__ __launch_bounds__(256) void k_adaln(
    const float* __restrict__ xsrc, const int* __restrict__ idx,
    const float* __restrict__ p, bf16* __restrict__ hout)
{
  const int r = blockIdx.x, t = threadIdx.x;
  bf16* orow = hout + (size_t)r * D_;
  if (r >= M_TOT) {
    bf16x4 z = {(bf16)0.f, (bf16)0.f, (bf16)0.f, (bf16)0.f};
    ((bf16x4*)orow)[t] = z;
    return;
  }
  const int b = r / KEEP, j = r - b * KEEP;
  const int s = idx[b * KEEP + j];
  const float* xr = xsrc + ((size_t)(b * S_ + s)) * D_;
  float4 v = ((const float4*)xr)[t];
  __shared__ float red[8];
  float sum = v.x + v.y + v.z + v.w;
  for (int o = 32; o > 0; o >>= 1) sum += __shfl_down(sum, o);
  const int lane = t & 63, w = t >> 6;
  if (lane == 0) red[w] = sum;
  __syncthreads();
  const float mu = (red[0] + red[1] + red[2] + red[3]) * (1.f / D_);
  const float dx = v.x - mu, dy = v.y - mu, dz = v.z - mu, dw = v.w - mu;
  float vs = dx * dx + dy * dy + dz * dz + dw * dw;
  for (int o = 32; o > 0; o >>= 1) vs += __shfl_down(vs, o);
  if (lane == 0) red[4 + w] = vs;
  __syncthreads();
  const float rstd = rsqrtf((red[4] + red[5] + red[6] + red[7]) * (1.f / D_) + EPS);
  const float* gp = p + (size_t)b * 2 * D_;
  float4 g  = ((const float4*)gp)[t];
  float4 be = ((const float4*)(gp + D_))[t];
  bf16x4 o;
  o[0] = (bf16)(dx * rstd * (1.f + g.x) + be.x);
  o[1] = (bf16)(dy * rstd * (1.f + g.y) + be.y);
  o[2] = (bf16)(dz * rstd * (1.f + g.z) + be.z);
  o[3] = (bf16)(dw * rstd * (1.f + g.w) + be.w);
  ((bf16x4*)orow)[t] = o;
}

// ---------------- GEMM 128xBN, BK=64 (3-bit swizzle: 0 bank conflicts) ------
// 2-phase dbuf, hoisted staging pointers, bijective XCD remap.
// MODE 0: bias (+QSCALE on Q third) -> bf16. MODE 1: bias+gelu -> bf16.
// MODE 2: bias, then resid[row(m)][n] += gate[n]*v (gathered residual).
template <int BN, int MODE>
__global__ __launch_bounds__(256) void k_gemm(
    const bf16* __restrict__ A, const bf16* __restrict__ W,
    const float* __restrict__ bias, bf16* __restrict__ Cbf,
    const float* __restrict__ gate, const int* __restrict__ idx,
    float* __restrict__ resid, int N, int K, int gn)
{
  constexpr int WN = BN / 2;      // per-wave N span
  constexpr int NJ = WN / 16;     // N fragments per wave
  constexpr int WIT = BN / 32;    // W staging iterations
  __shared__ bf16 As[2][128 * 64];
  __shared__ bf16 Ws[2][BN * 64];
  const int t = threadIdx.x, lane = t & 63;
  const int w = t >> 6, wr = w >> 1, wc = w & 1;
  const int fr = lane & 15, fq = lane >> 4;

  // bijective XCD-contiguous remap (m204)
  const int nwg = gridDim.x, orig = blockIdx.x;
  const int q8 = nwg >> 3, r8 = nwg & 7;
  const int xc = orig & 7, pos = orig >> 3;
  const int wgid = (xc < r8 ? xc * (q8 + 1) : r8 * (q8 + 1) + (xc - r8) * q8) + pos;
  const int bm = wgid / gn, bn = wgid - bm * gn;

  const bf16* Ab = A + (size_t)bm * 128 * K;
  const bf16* Wb = W + (size_t)bn * BN * K;

  // tile-invariant per-thread staging pointers (advance += 64 per tile)
  const bf16* pA[4];
  const bf16* pW[WIT];
#pragma unroll
  for (int it = 0; it < 4; ++it) {
    const int e = it * 256 + t;
    const int row = e >> 3, pc = e & 7;
    const int lc = pc ^ (row & 7);
    pA[it] = Ab + (size_t)row * K + lc * 8;
  }
#pragma unroll
  for (int it = 0; it < WIT; ++it) {
    const int e = it * 256 + t;
    const int row = e >> 3, pc = e & 7;
    const int lc = pc ^ (row & 7);
    pW[it] = Wb + (size_t)row * K + lc * 8;
  }

  auto stage = [&](int buf) {
#pragma unroll
    for (int it = 0; it < 4; ++it) {
      GLOAD_LDS(pA[it], &As[buf][0] + (it * 256 + t) * 8);
      pA[it] += 64;
    }
#pragma unroll
    for (int it = 0; it < WIT; ++it) {
      GLOAD_LDS(pW[it], &Ws[buf][0] + (it * 256 + t) * 8);
      pW[it] += 64;
    }
  };

  f32x4 acc[4][NJ] = {};
  stage(0);
  const int nkt = K >> 6;
  int cur = 0;
  for (int kt = 0; kt < nkt; ++kt) {
    __syncthreads();                   // stage(cur) landed; prev reads done
    if (kt + 1 < nkt) stage(cur ^ 1);
    const char* Al = (const char*)&As[cur][0];
    const char* Wl = (const char*)&Ws[cur][0];
#pragma unroll
    for (int kk = 0; kk < 2; ++kk) {
      bf16x8 af[4], wf[NJ];
#pragma unroll
      for (int i = 0; i < 4; ++i)
        af[i] = *(const bf16x8*)(Al + (wr * 64 + i * 16 + fr) * 128 +
                                 (((kk * 4 + fq) ^ (fr & 7)) << 4));
#pragma unroll
      for (int j = 0; j < NJ; ++j)
        wf[j] = *(const bf16x8*)(Wl + (wc * WN + j * 16 + fr) * 128 +
                                 (((kk * 4 + fq) ^ (fr & 7)) << 4));
#pragma unroll
      for (int i = 0; i < 4; ++i)
#pragma unroll
        for (int j = 0; j < NJ; ++j)
          acc[i][j] = mfma16(af[i], wf[j], acc[i][j]);
    }
    cur ^= 1;
  }

  if (MODE == 2) {
    // per output row compute idx/gather once, then sweep n
#pragma unroll
    for (int i = 0; i < 4; ++i) {
#pragma unroll
      for (int r = 0; r < 4; ++r) {
        const int m = bm * 128 + wr * 64 + i * 16 + fq * 4 + r;
        if (m < M_TOT) {
          const int b = m / KEEP, jj = m - b * KEEP;
          const int s = idx[b * KEEP + jj];
          float* rp = resid + ((size_t)(b * S_ + s)) * D_ + bn * BN + wc * WN + fr;
          const float* gp = gate + bn * BN + wc * WN + fr;
          const float* bp = bias + bn * BN + wc * WN + fr;
#pragma unroll
          for (int j = 0; j < NJ; ++j)
            rp[j * 16] += gp[j * 16] * (acc[i][j][r] + bp[j * 16]);
        }
      }
    }
  } else {
#pragma unroll
    for (int i = 0; i < 4; ++i) {
#pragma unroll
      for (int j = 0; j < NJ; ++j) {
#pragma unroll
        for (int r = 0; r < 4; ++r) {
          const int m = bm * 128 + wr * 64 + i * 16 + fq * 4 + r;
          const int n = bn * BN + wc * WN + j * 16 + fr;
          float v = acc[i][j][r] + bias[n];
          if (MODE == 0) {
            if (n < D_) v *= QSCALE;
            Cbf[(size_t)m * N + n] = (bf16)v;
          } else {
            float gl = 0.5f * v * (1.f + erff(v * 0.70710678118654752f));
            Cbf[(size_t)m * N + n] = (bf16)gl;
          }
        }
      }
    }
  }
}

// ---------------- flash attention: 8-wave blocks, 128 q-rows/block -----------
// Per-wave state identical to the 4-wave version (16 q-rows, VGPR ~80); the
// 8 waves share ONE K/V double-buffer -> 2x waves/CU resident and half the
// K/V staging traffic per q-row. Swapped-QK^T + in-register softmax +
// hoisted V tr-reads + XCD-contiguous grid (768 = 8*96).
__global__ __launch_bounds__(512) void k_attn(const bf16* __restrict__ qkv,
                                              bf16* __restrict__ out)
{
  __shared__ bf16 Klds[2][64 * 64];
  __shared__ bf16 Vlds[2][64 * 64];

  const int t = threadIdx.x;
  const int lane = t & 63, w = t >> 6;       // w in 0..7
  const int fr = lane & 15, fq = lane >> 4;

  const int orig = blockIdx.x;
  const int wgid = (orig & 7) * 96 + (orig >> 3);
  const int qtb = wgid % QT128;
  const int hb = wgid / QT128;
  const int h = hb & 15, b = hb >> 4;

  const size_t rowbase = (size_t)b * KEEP;
  const size_t RS = 3 * D_;
  const bf16* kbase = qkv + rowbase * RS + D_ + h * 64;
  const bf16* vbase = qkv + rowbase * RS + 2 * D_ + h * 64;

  const int wq0 = qtb * 128 + w * 16;
  const int qrow = min(wq0 + fr, KEEP - 1);
  const bf16* qp = qkv + (rowbase + qrow) * RS + h * 64 + fq * 8;
  const bf16x8 qf0 = *(const bf16x8*)qp;          // Q as B-operand, d<32
  const bf16x8 qf1 = *(const bf16x8*)(qp + 32);   // d>=32

  f32x4 o[4] = {};
  float mrow = -INFINITY, lrow = 0.f;

  // ---- staging: 512 threads cover the 512 16B-chunks of each K/V tile
  auto kaddr = [&](int p, int kv) {
    const int row = p >> 3, c8p = p & 7;
    const int c8 = c8p ^ ((row & 7) ^ (row >> 3));
    const int gr = min(kv + row, KEEP - 1);
    return kbase + (size_t)gr * RS + c8 * 8;
  };
  auto vaddr = [&](int p, int kv) {
    const int db = p >> 7, ksub = (p >> 3) & 15, jr = (p >> 1) & 3,
              c8lo = p & 1;
    const int vrow = ksub * 4 + jr, vc8 = db * 2 + c8lo;
    const int gr = min(kv + vrow, KEEP - 1);
    return vbase + (size_t)gr * RS + vc8 * 8;
  };
  const bf16* kp = kaddr(t, 0);
  const bf16* vp = vaddr(t, 0);

  auto stage_fast = [&](int buf) {
    GLOAD_LDS(kp, &Klds[buf][0] + t * 8);
    GLOAD_LDS(vp, &Vlds[buf][0] + t * 8);
    kp += 64 * RS; vp += 64 * RS;
  };
  auto stage_last = [&](int buf, int kv) {   // clamped (final tile)
    GLOAD_LDS(kaddr(t, kv), &Klds[buf][0] + t * 8);
    GLOAD_LDS(vaddr(t, kv), &Vlds[buf][0] + t * 8);
  };

  stage_fast(0);
  int cur = 0;

  const unsigned vbase_lds0 =
      (unsigned)(size_t)(__attribute__((address_space(3))) bf16*)&Vlds[0][0];
  const unsigned vbase_lds1 =
      (unsigned)(size_t)(__attribute__((address_space(3))) bf16*)&Vlds[1][0];

  for (int ti = 0; ti < NKV; ++ti) {
    const int kv = ti * 64;
    __syncthreads();                   // stage(cur) landed; prev reads done
    if (ti < NKV - 2) stage_fast(cur ^ 1);
    else if (ti == NKV - 2) stage_last(cur ^ 1, kv + 64);

    const char* Kl = (const char*)&Klds[cur][0];

    f32x4 sc[4];
    __builtin_amdgcn_s_setprio(1);
#pragma unroll
    for (int f = 0; f < 4; ++f) {
      const int row = ((f >> 1) << 5) + ((fr >> 2) << 3) + ((f & 1) << 1) +
                      (fr & 1) + (((fr >> 1) & 1) << 2);
      const int swz = (row & 7) ^ (row >> 3);
      const bf16x8 kf0 = *(const bf16x8*)(Kl + row * 128 + ((fq ^ swz) << 4));
      const bf16x8 kf1 =
          *(const bf16x8*)(Kl + row * 128 + (((fq ^ 4) ^ swz) << 4));
      f32x4 s = {0.f, 0.f, 0.f, 0.f};
      s = mfma16(kf0, qf0, s);
      s = mfma16(kf1, qf1, s);
      sc[f] = s;
    }
    __builtin_amdgcn_s_setprio(0);

    // issue ALL V tr-reads now (no wait): overlap the softmax VALU
    const unsigned vb =
        (cur ? vbase_lds1 : vbase_lds0) + ((unsigned)fq << 7);
    bf16x4 v0[8], v1[8];
    asm volatile(
        "ds_read_b64_tr_b16 %0, %8 offset:0\n\t"
        "ds_read_b64_tr_b16 %1, %8 offset:128\n\t"
        "ds_read_b64_tr_b16 %2, %8 offset:2048\n\t"
        "ds_read_b64_tr_b16 %3, %8 offset:2176\n\t"
        "ds_read_b64_tr_b16 %4, %8 offset:4096\n\t"
        "ds_read_b64_tr_b16 %5, %8 offset:4224\n\t"
        "ds_read_b64_tr_b16 %6, %8 offset:6144\n\t"
        "ds_read_b64_tr_b16 %7, %8 offset:6272"
        : "=&v"(v0[0]), "=&v"(v0[1]), "=&v"(v0[2]), "=&v"(v0[3]),
          "=&v"(v0[4]), "=&v"(v0[5]), "=&v"(v0[6]), "=&v"(v0[7])
        : "v"(vb));
    asm volatile(
        "ds_read_b64_tr_b16 %0, %8 offset:1024\n\t"
        "ds_read_b64_tr_b16 %1, %8 offset:1152\n\t"
        "ds_read_b64_tr_b16 %2, %8 offset:3072\n\t"
        "ds_read_b64_tr_b16 %3, %8 offset:3200\n\t"
        "ds_read_b64_tr_b16 %4, %8 offset:5120\n\t"
        "ds_read_b64_tr_b16 %5, %8 offset:5248\n\t"
        "ds_read_b64_tr_b16 %6, %8 offset:7168\n\t"
        "ds_read_b64_tr_b16 %7, %8 offset:7296"
        : "=&v"(v1[0]), "=&v"(v1[1]), "=&v"(v1[2]), "=&v"(v1[3]),
          "=&v"(v1[4]), "=&v"(v1[5]), "=&v"(v1[6]), "=&v"(v1[7])
        : "v"(vb));

    if (ti == NKV - 1) {
#pragma unroll
      for (int f = 0; f < 4; ++f)
#pragma unroll
        for (int r = 0; r < 4; ++r) {
          const int kl = ((f >> 1) << 5) + (fq << 3) + ((f & 1) << 1) +
                         (r & 1) + ((r >> 1) << 2);
          if (kv + kl >= KEEP) sc[f][r] = -INFINITY;
        }
    }
    float m0 = fmaxf(fmaxf(sc[0][0], sc[0][1]), sc[0][2]);
    float m1 = fmaxf(fmaxf(sc[0][3], sc[1][0]), sc[1][1]);
    float m2 = fmaxf(fmaxf(sc[1][2], sc[1][3]), sc[2][0]);
    float m3 = fmaxf(fmaxf(sc[2][1], sc[2][2]), sc[2][3]);
    float m4 = fmaxf(fmaxf(sc[3][0], sc[3][1]), sc[3][2]);
    float mx = fmaxf(fmaxf(m0, m1), m2);
    mx = fmaxf(fmaxf(mx, m3), fmaxf(m4, sc[3][3]));
    mx = fmaxf(mx, __shfl_xor(mx, 16));
    mx = fmaxf(mx, __shfl_xor(mx, 32));

    const bool noresc = __all(mx <= mrow + 8.f);
    const float mnew = noresc ? mrow : fmaxf(mrow, mx);
    float ps = 0.f;
    bf16 pe[4][4];
#pragma unroll
    for (int f = 0; f < 4; ++f)
#pragma unroll
      for (int r = 0; r < 4; ++r) {
        const float pv = exp2f(sc[f][r] - mnew);
        ps += pv;
        pe[f][r] = (bf16)pv;
      }
    ps += __shfl_xor(ps, 16);
    ps += __shfl_xor(ps, 32);
    if (!noresc) {
      const float fac = exp2f(mrow - mnew);
      lrow *= fac;
#pragma unroll
      for (int db = 0; db < 4; ++db) {
        o[db][0] *= fac; o[db][1] *= fac; o[db][2] *= fac; o[db][3] *= fac;
      }
      mrow = mnew;
    }
    lrow += ps;

    const bf16x8 pb[2] = {
        {pe[0][0], pe[0][1], pe[1][0], pe[1][1],
         pe[0][2], pe[0][3], pe[1][2], pe[1][3]},
        {pe[2][0], pe[2][1], pe[3][0], pe[3][1],
         pe[2][2], pe[2][3], pe[3][2], pe[3][3]}};

    asm volatile("s_waitcnt lgkmcnt(0)" ::: "memory");
    __builtin_amdgcn_sched_barrier(0);

    const bf16x8 vf00 = __builtin_shufflevector(v0[0], v0[1], 0,1,2,3,4,5,6,7);
    const bf16x8 vf01 = __builtin_shufflevector(v0[2], v0[3], 0,1,2,3,4,5,6,7);
    const bf16x8 vf02 = __builtin_shufflevector(v0[4], v0[5], 0,1,2,3,4,5,6,7);
    const bf16x8 vf03 = __builtin_shufflevector(v0[6], v0[7], 0,1,2,3,4,5,6,7);
    const bf16x8 vf10 = __builtin_shufflevector(v1[0], v1[1], 0,1,2,3,4,5,6,7);
    const bf16x8 vf11 = __builtin_shufflevector(v1[2], v1[3], 0,1,2,3,4,5,6,7);
    const bf16x8 vf12 = __builtin_shufflevector(v1[4], v1[5], 0,1,2,3,4,5,6,7);
    const bf16x8 vf13 = __builtin_shufflevector(v1[6], v1[7], 0,1,2,3,4,5,6,7);
    __builtin_amdgcn_s_setprio(1);
    o[0] = mfma16(vf00, pb[0], o[0]);
    o[1] = mfma16(vf01, pb[0], o[1]);
    o[2] = mfma16(vf02, pb[0], o[2]);
    o[3] = mfma16(vf03, pb[0], o[3]);
    o[0] = mfma16(vf10, pb[1], o[0]);
    o[1] = mfma16(vf11, pb[1], o[1]);
    o[2] = mfma16(vf12, pb[1], o[2]);
    o[3] = mfma16(vf13, pb[1], o[3]);
    __builtin_amdgcn_s_setprio(0);
    cur ^= 1;
  }

  const int q = wq0 + fr;
  if (q < KEEP) {
    const float inv = 1.f / lrow;
#pragma unroll
    for (int db = 0; db < 4; ++db) {
      bf16x4 wv = {(bf16)(o[db][0] * inv), (bf16)(o[db][1] * inv),
                   (bf16)(o[db][2] * inv), (bf16)(o[db][3] * inv)};
      *(bf16x4*)(out + (rowbase + q) * (size_t)D_ + h * 64 + db * 16 + fq * 4) =
          wv;
    }
  }
}

// ----------------------------------------------------------------------------
extern "C" void kernel_launch(void* const* d_in, const int* in_sizes, int n_in,
                              void* d_out, int out_size, void* d_ws, size_t ws_size,
                              hipStream_t stream)
{
  (void)in_sizes; (void)n_in; (void)out_size; (void)ws_size;
  const float* x      = (const float*)d_in[0];
  const float* t_emb  = (const float*)d_in[1];
  const float* tr_w1  = (const float*)d_in[2];
  const float* tr_b1  = (const float*)d_in[3];
  const float* tr_w2  = (const float*)d_in[4];
  const float* tr_b2  = (const float*)d_in[5];
  const float* ln1_w  = (const float*)d_in[6];
  const float* ln1_b  = (const float*)d_in[7];
  const float* ln2_w  = (const float*)d_in[8];
  const float* ln2_b  = (const float*)d_in[9];
  const float* in_w   = (const float*)d_in[10];
  const float* in_b   = (const float*)d_in[11];
  const float* out_w  = (const float*)d_in[12];
  const float* out_b  = (const float*)d_in[13];
  const float* f1_w   = (const float*)d_in[14];
  const float* f1_b   = (const float*)d_in[15];
  const float* f2_w   = (const float*)d_in[16];
  const float* f2_b   = (const float*)d_in[17];
  const float* gate_a = (const float*)d_in[18];
  const float* gate_f = (const float*)d_in[19];

  char* ws = (char*)d_ws;
  size_t off = 0;
  auto alloc = [&](size_t bytes) -> char* {
    char* p = ws + off;
    off = (off + bytes + 255) & ~(size_t)255;
    return p;
  };
  double* imp  = (double*)alloc((size_t)B_ * S_ * 8);
  double* hid  = (double*)alloc((size_t)B_ * S_ * 32 * 8);
  int* rank    = (int*)alloc((size_t)B_ * S_ * 4);
  int* idx     = (int*)alloc((size_t)B_ * KEEP * 4);
  float* p1    = (float*)alloc((size_t)B_ * 2 * D_ * 4);
  float* p2    = (float*)alloc((size_t)B_ * 2 * D_ * 4);
  bf16* w_in   = (bf16*)alloc((size_t)3 * D_ * D_ * 2);
  bf16* w_out  = (bf16*)alloc((size_t)D_ * D_ * 2);
  bf16* w_f1   = (bf16*)alloc((size_t)DFF_ * D_ * 2);
  bf16* w_f2   = (bf16*)alloc((size_t)D_ * DFF_ * 2);
  bf16* h_bf   = (bf16*)alloc((size_t)MPAD * D_ * 2);
  bf16* big    = (bf16*)alloc((size_t)MPAD * (3 * D_ + D_) * 2);
  bf16* qkv    = big;
  bf16* attn   = big + (size_t)MPAD * 3 * D_;
  bf16* ffn1   = big;   // overlays qkv+attn (both dead by then)

  k_prep<<<8704, 256, 0, stream>>>(
      x, tr_w1, hid,
      in_w, out_w, f1_w, f2_w, w_in, w_out, w_f1, w_f2,
      (float*)d_out,
      t_emb, ln1_w, ln1_b, p1, ln2_w, ln2_b, p2);
  k_imptail<<<B_ * S_ / 256, 256, 0, stream>>>(hid, tr_b1, tr_w2, tr_b2, imp);
  k_rank<<<B_ * 32, 256, 0, stream>>>(imp, rank);
  k_compact<<<B_, 256, 0, stream>>>(rank, idx);

  k_adaln<<<MPAD, 256, 0, stream>>>(x, idx, p1, h_bf);
  k_gemm<128, 0><<<46 * 24, 256, 0, stream>>>(
      h_bf, w_in, in_b, qkv, nullptr, nullptr, nullptr, 3 * D_, D_, 24);
  k_attn<<<QT128 * H_ * B_, 512, 0, stream>>>(qkv, attn);
  k_gemm<64, 2><<<46 * 16, 256, 0, stream>>>(
      attn, w_out, out_b, nullptr, gate_a, idx, (float*)d_out, D_, D_, 16);
  k_adaln<<<MPAD, 256, 0, stream>>>((const float*)d_out, idx, p2, h_bf);
  k_gemm<128, 1><<<46 * 32, 256, 0, stream>>>(
      h_bf, w_f1, f1_b, ffn1, nullptr, nullptr, nullptr, DFF_, D_, 32);
  k_gemm<64, 2><<<46 * 16, 256, 0, stream>>>(
      ffn1, w_f2, f2_b, nullptr, gate_f, idx, (float*)d_out, D_, DFF_, 16);
}